// Round 3
// baseline (834.201 us; speedup 1.0000x reference)
//
#include <hip/hip_runtime.h>

#define N_NODES 100000
#define N_EDGES 3200000
#define DIM 128
#define GRP 8            // column groups: G stored [GRP][N_NODES][GCOLS] bf16
#define GCOLS 16         // 16 cols * 2B = 32B slice per node per group; slice = 3.2MB -> fits 4MB XCD L2
#define NBUCK 391        // ceil(100000/256) buckets of 256 nodes (dst>>8)
#define NBP 392          // padded
#define EB_BLOCKS 782    // ceil(3.2M / 4096) edge blocks (4096 edges/block)

// ---------------- helpers ----------------

__device__ __forceinline__ unsigned rne_bf16(float f) {
    unsigned u = __builtin_bit_cast(unsigned, f);
    return (u + 0x7FFFu + ((u >> 16) & 1u)) >> 16;
}
__device__ __forceinline__ float bf16lo(unsigned u) {
    return __builtin_bit_cast(float, u << 16);
}
__device__ __forceinline__ float bf16hi(unsigned u) {
    return __builtin_bit_cast(float, u & 0xFFFF0000u);
}

// ---------------- CSR build: bucket counting sort ----------------

// B1: per-block LDS hist of 4096 edges into 392 buckets; 1 global atomic per (block,bucket)
__global__ __launch_bounds__(256) void bhist_k(const int* __restrict__ dst,
                                               int* __restrict__ bucketTotal) {
    __shared__ int h[NBP];
    int tid = threadIdx.x;
    for (int i = tid; i < NBP; i += 256) h[i] = 0;
    __syncthreads();
#pragma unroll
    for (int c = 0; c < 4; c++) {
        int e = blockIdx.x * 4096 + c * 1024 + tid * 4;
        if (e < N_EDGES) {
            int4 d4 = ((const int4*)dst)[e >> 2];
            atomicAdd(&h[d4.x >> 8], 1);
            atomicAdd(&h[d4.y >> 8], 1);
            atomicAdd(&h[d4.z >> 8], 1);
            atomicAdd(&h[d4.w >> 8], 1);
        }
    }
    __syncthreads();
    for (int i = tid; i < NBP; i += 256)
        if (h[i] > 0) atomicAdd(&bucketTotal[i], h[i]);
}

// B2: exclusive scan of 392 bucket totals -> bucketBase[0..392], init cursors
__global__ __launch_bounds__(512) void bscan_k(const int* __restrict__ bucketTotal,
                                               int* __restrict__ bucketBase,
                                               int* __restrict__ bucketCursor) {
    __shared__ int tmp[512];
    int tid = threadIdx.x;
    int v = (tid < NBP) ? bucketTotal[tid] : 0;
    tmp[tid] = v;
    __syncthreads();
    for (int off = 1; off < 512; off <<= 1) {
        int x = tmp[tid];
        if (tid >= off) x += tmp[tid - off];
        __syncthreads();
        tmp[tid] = x;
        __syncthreads();
    }
    if (tid < NBP) {
        int excl = tmp[tid] - v;
        bucketBase[tid] = excl;
        bucketCursor[tid] = excl;
        if (tid == NBP - 1) bucketBase[NBP] = tmp[tid];
    }
}

// B3: re-hist per block, reserve per-bucket runs, scatter (src,dst) into bucket regions
__global__ __launch_bounds__(256) void bscatter_k(const int* __restrict__ src,
                                                  const int* __restrict__ dst,
                                                  int* __restrict__ bucketCursor,
                                                  int2* __restrict__ ebuf) {
    __shared__ int h[NBP];
    __shared__ int lcur[NBP];
    int tid = threadIdx.x;
    for (int i = tid; i < NBP; i += 256) h[i] = 0;
    __syncthreads();
#pragma unroll
    for (int c = 0; c < 4; c++) {
        int e = blockIdx.x * 4096 + c * 1024 + tid * 4;
        if (e < N_EDGES) {
            int4 d4 = ((const int4*)dst)[e >> 2];
            atomicAdd(&h[d4.x >> 8], 1);
            atomicAdd(&h[d4.y >> 8], 1);
            atomicAdd(&h[d4.z >> 8], 1);
            atomicAdd(&h[d4.w >> 8], 1);
        }
    }
    __syncthreads();
    for (int i = tid; i < NBP; i += 256)
        lcur[i] = (h[i] > 0) ? atomicAdd(&bucketCursor[i], h[i]) : 0;
    __syncthreads();
#pragma unroll
    for (int c = 0; c < 4; c++) {
        int e = blockIdx.x * 4096 + c * 1024 + tid * 4;
        if (e < N_EDGES) {
            int4 d4 = ((const int4*)dst)[e >> 2];
            int4 s4 = ((const int4*)src)[e >> 2];
            int p0 = atomicAdd(&lcur[d4.x >> 8], 1);
            int p1 = atomicAdd(&lcur[d4.y >> 8], 1);
            int p2 = atomicAdd(&lcur[d4.z >> 8], 1);
            int p3 = atomicAdd(&lcur[d4.w >> 8], 1);
            ebuf[p0] = make_int2(s4.x, d4.x);
            ebuf[p1] = make_int2(s4.y, d4.y);
            ebuf[p2] = make_int2(s4.z, d4.z);
            ebuf[p3] = make_int2(s4.w, d4.w);
        }
    }
}

// B4: one block per bucket: LDS count, scan -> offsets, LDS-cursor rank -> final csr
__global__ __launch_bounds__(256) void bfinal_k(const int2* __restrict__ ebuf,
                                                const int* __restrict__ bucketBase,
                                                int* __restrict__ offsets,
                                                int* __restrict__ csr) {
    __shared__ int h[256];
    __shared__ int sc[256];
    int tid = threadIdx.x;
    int b = blockIdx.x;
    int s = bucketBase[b], e = bucketBase[b + 1];
    h[tid] = 0;
    __syncthreads();
    for (int idx = s + tid; idx < e; idx += 256) {
        int2 ed = ebuf[idx];
        atomicAdd(&h[ed.y & 255], 1);
    }
    __syncthreads();
    sc[tid] = h[tid];
    __syncthreads();
    for (int off = 1; off < 256; off <<= 1) {
        int x = sc[tid];
        if (tid >= off) x += sc[tid - off];
        __syncthreads();
        sc[tid] = x;
        __syncthreads();
    }
    int excl = sc[tid] - h[tid];
    int node = b * 256 + tid;
    if (node < N_NODES) offsets[node] = s + excl;
    if (b == 0 && tid == 0) offsets[N_NODES] = N_EDGES;
    __syncthreads();
    h[tid] = s + excl;   // reuse as cursor
    __syncthreads();
    for (int idx = s + tid; idx < e; idx += 256) {
        int2 ed = ebuf[idx];
        int pos = atomicAdd(&h[ed.y & 255], 1);
        csr[pos] = ed.x;
    }
}

// ---------------- per-layer compute ----------------

// G[g][row][c] = row-th row of H@W, cols g*16..g*16+15, bf16 (RNE).
// Inner loop: round-0 form (round-1 k+=4 variant regressed ~100us; reverted);
// only the store addressing changed to the group-major layout.
__global__ __launch_bounds__(256) void gemm_k(const float* __restrict__ H,
                                              const float* __restrict__ W,
                                              unsigned short* __restrict__ G) {
    __shared__ float hs[64][128];
    int tid = threadIdx.x;
    int rowBase = blockIdx.x * 64;
    for (int i = tid; i < 64 * 32; i += 256) {
        int r = i >> 5, c4 = i & 31;
        int row = rowBase + r;
        float4 v = make_float4(0.f, 0.f, 0.f, 0.f);
        if (row < N_NODES) v = ((const float4*)(H + (size_t)row * DIM))[c4];
        ((float4*)&hs[r][0])[c4] = v;
    }
    __syncthreads();

    int tx = tid & 31, ty = tid >> 5;
    int c0 = tx * 4, r0 = ty * 8;
    float4 acc[8];
#pragma unroll
    for (int r = 0; r < 8; r++) acc[r] = make_float4(0.f, 0.f, 0.f, 0.f);

#pragma unroll 4
    for (int k = 0; k < DIM; k++) {
        float4 wv = *(const float4*)(W + (size_t)k * DIM + c0);
#pragma unroll
        for (int r = 0; r < 8; r++) {
            float a = hs[r0 + r][k];
            acc[r].x += a * wv.x;
            acc[r].y += a * wv.y;
            acc[r].z += a * wv.z;
            acc[r].w += a * wv.w;
        }
    }
    int gg = c0 >> 4, wc = c0 & 15;
#pragma unroll
    for (int r = 0; r < 8; r++) {
        int row = rowBase + r0 + r;
        if (row < N_NODES) {
            uint2 pk;
            pk.x = rne_bf16(acc[r].x) | (rne_bf16(acc[r].y) << 16);
            pk.y = rne_bf16(acc[r].z) | (rne_bf16(acc[r].w) << 16);
            *(uint2*)(G + ((size_t)gg * N_NODES + row) * GCOLS + wc) = pk;
        }
    }
}

__device__ __forceinline__ void accum8(float* acc, uint4 v) {
    acc[0] += bf16lo(v.x); acc[1] += bf16hi(v.x);
    acc[2] += bf16lo(v.y); acc[3] += bf16hi(v.y);
    acc[4] += bf16lo(v.z); acc[5] += bf16hi(v.z);
    acc[6] += bf16lo(v.w); acc[7] += bf16hi(v.w);
}

// Column-group aggregation: block handles group g = blockIdx&7 (round-robin
// block->XCD dispatch pins each 3.2MB G-slice into one XCD's 4MB L2 -> gathers
// become L2 hits instead of L2 misses). 4 nodes/wave: quarter = lane>>4 picks
// the node; within a quarter, e8 = (lane&15)>>1 is the edge slot (8 edges per
// gather instr), h = lane&1 picks the 16B half-slice (8 cols). 4 sub-batches
// (32 edges/node) issued before accumulation (sched_barrier keeps them in
// flight). Butterfly reduce xor 2/4/8 serves all 4 nodes at once.
__global__ __launch_bounds__(256) void agg_k(const unsigned short* __restrict__ G,
                                             const int* __restrict__ off,
                                             const int* __restrict__ csr,
                                             const float* __restrict__ bias,
                                             const float* __restrict__ epsp,
                                             float* __restrict__ out) {
    int tid = threadIdx.x;
    int lane = tid & 63;
    int wid = tid >> 6;
    int g = blockIdx.x & 7;
    int chunk = blockIdx.x >> 3;
    int quarter = lane >> 4;
    int ql = lane & 15;
    int e8 = ql >> 1;
    int h = ql & 1;
    int node = chunk * 16 + wid * 4 + quarter;
    const unsigned short* Gg = G + (size_t)g * N_NODES * GCOLS;

    float e1 = 1.0f + epsp[0];
    int s = off[node], e = off[node + 1];
    int n = e - s;
    const int* cl = csr + s;

    float acc[8] = {0.f, 0.f, 0.f, 0.f, 0.f, 0.f, 0.f, 0.f};

    // wave-uniform trip count = max degree over the wave's 4 nodes
    int nmax = n;
    nmax = max(nmax, __shfl_xor(nmax, 16));
    nmax = max(nmax, __shfl_xor(nmax, 32));
    int nm1 = (n > 0) ? (n - 1) : 0;

    for (int i = 0; i < nmax; i += 32) {
        int idxv[4];
        bool val[4];
#pragma unroll
        for (int b = 0; b < 4; b++) {
            int pos = i + b * 8 + e8;
            val[b] = pos < n;
            int pc = val[b] ? pos : nm1;
            idxv[b] = cl[pc];
        }
        uint4 v[4];
#pragma unroll
        for (int b = 0; b < 4; b++)
            v[b] = *(const uint4*)(Gg + (size_t)idxv[b] * GCOLS + h * 8);
        __builtin_amdgcn_sched_barrier(0);
#pragma unroll
        for (int b = 0; b < 4; b++)
            if (val[b]) accum8(acc, v[b]);
    }

    // butterfly reduce over edge slots (lane bits 1..3); h (bit 0) preserved
#pragma unroll
    for (int j = 0; j < 8; j++) {
        acc[j] += __shfl_xor(acc[j], 2);
        acc[j] += __shfl_xor(acc[j], 4);
        acc[j] += __shfl_xor(acc[j], 8);
    }

    if (e8 == 0) {   // 2 lanes per node: h=0 -> cols 0..7 of group, h=1 -> cols 8..15
        uint4 sv = *(const uint4*)(Gg + (size_t)node * GCOLS + h * 8);
        int colb = g * GCOLS + h * 8;
        float4 b0 = *(const float4*)(bias + colb);
        float4 b1 = *(const float4*)(bias + colb + 4);
        float* op = out + (size_t)node * DIM + colb;
        float4 r0, r1;
        r0.x = acc[0] + e1 * bf16lo(sv.x) + b0.x;
        r0.y = acc[1] + e1 * bf16hi(sv.x) + b0.y;
        r0.z = acc[2] + e1 * bf16lo(sv.y) + b0.z;
        r0.w = acc[3] + e1 * bf16hi(sv.y) + b0.w;
        r1.x = acc[4] + e1 * bf16lo(sv.z) + b1.x;
        r1.y = acc[5] + e1 * bf16hi(sv.z) + b1.y;
        r1.z = acc[6] + e1 * bf16lo(sv.w) + b1.z;
        r1.w = acc[7] + e1 * bf16hi(sv.w) + b1.w;
        *(float4*)op = r0;
        *(float4*)(op + 4) = r1;
    }
}

// ---------------- launch ----------------

extern "C" void kernel_launch(void* const* d_in, const int* in_sizes, int n_in,
                              void* d_out, int out_size, void* d_ws, size_t ws_size,
                              hipStream_t stream) {
    const float* feats = (const float*)d_in[0];
    const int* esrc = (const int*)d_in[1];
    const int* edst = (const int*)d_in[2];
    const float* Wm[3] = {(const float*)d_in[3], (const float*)d_in[6], (const float*)d_in[9]};
    const float* Bv[3] = {(const float*)d_in[4], (const float*)d_in[7], (const float*)d_in[10]};
    const float* Ev[3] = {(const float*)d_in[5], (const float*)d_in[8], (const float*)d_in[11]};
    float* out = (float*)d_out;

    char* ws = (char*)d_ws;
    unsigned short* bufG = (unsigned short*)(ws);     // 25,600,000 B : [8][100000][16] bf16
    int* csr        = (int*)(ws + 25600000);          // 12,800,000 B
    int2* ebuf      = (int2*)(ws + 38400000);         // 25,600,000 B (src,dst) bucketed
    int* offsets    = (int*)(ws + 64000000);          //    400,004 B
    int* bucketTotal= (int*)(ws + 64400128);          //      1,568 B
    int* bucketBase = (int*)(ws + 64401792);          //      1,572 B
    int* bucketCur  = (int*)(ws + 64403456);          //      1,568 B

    // CSR build: bucket counting sort
    hipMemsetAsync(bucketTotal, 0, NBP * sizeof(int), stream);
    bhist_k<<<EB_BLOCKS, 256, 0, stream>>>(edst, bucketTotal);
    bscan_k<<<1, 512, 0, stream>>>(bucketTotal, bucketBase, bucketCur);
    bscatter_k<<<EB_BLOCKS, 256, 0, stream>>>(esrc, edst, bucketCur, ebuf);
    bfinal_k<<<NBUCK, 256, 0, stream>>>(ebuf, bucketBase, offsets, csr);

    // 3 GIN layers: g = h @ W  (bufG, bf16, group-major);  h' = (1+eps)g + agg(g) + b
    const float* h = feats;
    for (int l = 0; l < 3; l++) {
        gemm_k<<<(N_NODES + 63) / 64, 256, 0, stream>>>(h, Wm[l], bufG);
        agg_k<<<GRP * (N_NODES / 16), 256, 0, stream>>>(bufG, offsets, csr, Bv[l], Ev[l], out);
        h = out;
    }
}

// Round 4
// 822.515 us; speedup vs baseline: 1.0142x; 1.0142x over previous
//
#include <hip/hip_runtime.h>

#define N_NODES 100000
#define N_EDGES 3200000
#define DIM 128
#define GRP 8            // column groups: G stored [GRP][N_NODES+1][GCOLS] bf16
#define GCOLS 16         // 16 cols * 2B = 32B slice per node per group; slice = 3.2MB -> fits 4MB XCD L2
#define GROWS (N_NODES + 1)   // +1: sentinel all-zero row for csr padding
#define NBUCK 391        // ceil(100000/256) buckets of 256 nodes (dst>>8)
#define NBP 392          // padded
#define EB_BLOCKS 782    // ceil(3.2M / 4096) edge blocks (4096 edges/block)
#define BSLACK 2048      // per-bucket csr padding slack (>= 256 nodes * 7)

// ---------------- helpers ----------------

__device__ __forceinline__ unsigned rne_bf16(float f) {
    unsigned u = __builtin_bit_cast(unsigned, f);
    return (u + 0x7FFFu + ((u >> 16) & 1u)) >> 16;
}
__device__ __forceinline__ float bf16lo(unsigned u) {
    return __builtin_bit_cast(float, u << 16);
}
__device__ __forceinline__ float bf16hi(unsigned u) {
    return __builtin_bit_cast(float, u & 0xFFFF0000u);
}

// ---------------- CSR build: bucket counting sort ----------------

// B1: per-block LDS hist of 4096 edges into 392 buckets; 1 global atomic per (block,bucket)
__global__ __launch_bounds__(256) void bhist_k(const int* __restrict__ dst,
                                               int* __restrict__ bucketTotal) {
    __shared__ int h[NBP];
    int tid = threadIdx.x;
    for (int i = tid; i < NBP; i += 256) h[i] = 0;
    __syncthreads();
#pragma unroll
    for (int c = 0; c < 4; c++) {
        int e = blockIdx.x * 4096 + c * 1024 + tid * 4;
        if (e < N_EDGES) {
            int4 d4 = ((const int4*)dst)[e >> 2];
            atomicAdd(&h[d4.x >> 8], 1);
            atomicAdd(&h[d4.y >> 8], 1);
            atomicAdd(&h[d4.z >> 8], 1);
            atomicAdd(&h[d4.w >> 8], 1);
        }
    }
    __syncthreads();
    for (int i = tid; i < NBP; i += 256)
        if (h[i] > 0) atomicAdd(&bucketTotal[i], h[i]);
}

// B2: exclusive scan of 392 bucket totals -> bucketBase[0..392], init cursors
__global__ __launch_bounds__(512) void bscan_k(const int* __restrict__ bucketTotal,
                                               int* __restrict__ bucketBase,
                                               int* __restrict__ bucketCursor) {
    __shared__ int tmp[512];
    int tid = threadIdx.x;
    int v = (tid < NBP) ? bucketTotal[tid] : 0;
    tmp[tid] = v;
    __syncthreads();
    for (int off = 1; off < 512; off <<= 1) {
        int x = tmp[tid];
        if (tid >= off) x += tmp[tid - off];
        __syncthreads();
        tmp[tid] = x;
        __syncthreads();
    }
    if (tid < NBP) {
        int excl = tmp[tid] - v;
        bucketBase[tid] = excl;
        bucketCursor[tid] = excl;
        if (tid == NBP - 1) bucketBase[NBP] = tmp[tid];
    }
}

// B3: re-hist per block, reserve per-bucket runs, scatter PACKED (src<<8 | dst&255)
// into bucket regions (1 int/edge instead of int2: halves scatter bytes)
__global__ __launch_bounds__(256) void bscatter_k(const int* __restrict__ src,
                                                  const int* __restrict__ dst,
                                                  int* __restrict__ bucketCursor,
                                                  int* __restrict__ ebuf) {
    __shared__ int h[NBP];
    __shared__ int lcur[NBP];
    int tid = threadIdx.x;
    for (int i = tid; i < NBP; i += 256) h[i] = 0;
    __syncthreads();
#pragma unroll
    for (int c = 0; c < 4; c++) {
        int e = blockIdx.x * 4096 + c * 1024 + tid * 4;
        if (e < N_EDGES) {
            int4 d4 = ((const int4*)dst)[e >> 2];
            atomicAdd(&h[d4.x >> 8], 1);
            atomicAdd(&h[d4.y >> 8], 1);
            atomicAdd(&h[d4.z >> 8], 1);
            atomicAdd(&h[d4.w >> 8], 1);
        }
    }
    __syncthreads();
    for (int i = tid; i < NBP; i += 256)
        lcur[i] = (h[i] > 0) ? atomicAdd(&bucketCursor[i], h[i]) : 0;
    __syncthreads();
#pragma unroll
    for (int c = 0; c < 4; c++) {
        int e = blockIdx.x * 4096 + c * 1024 + tid * 4;
        if (e < N_EDGES) {
            int4 d4 = ((const int4*)dst)[e >> 2];
            int4 s4 = ((const int4*)src)[e >> 2];
            int p0 = atomicAdd(&lcur[d4.x >> 8], 1);
            int p1 = atomicAdd(&lcur[d4.y >> 8], 1);
            int p2 = atomicAdd(&lcur[d4.z >> 8], 1);
            int p3 = atomicAdd(&lcur[d4.w >> 8], 1);
            ebuf[p0] = (s4.x << 8) | (d4.x & 255);
            ebuf[p1] = (s4.y << 8) | (d4.y & 255);
            ebuf[p2] = (s4.z << 8) | (d4.z & 255);
            ebuf[p3] = (s4.w << 8) | (d4.w & 255);
        }
    }
}

// B4: one block per bucket: count, PADDED scan (each node's list padded to mult.
// of 8 with sentinel N_NODES -> branch-light agg loop), rank -> padded csr.
// offsets[node] = padded start; nbArr[node] = #8-edge batches.
__global__ __launch_bounds__(256) void bfinal_k(const int* __restrict__ ebuf,
                                                const int* __restrict__ bucketBase,
                                                int* __restrict__ offsets,
                                                int* __restrict__ nbArr,
                                                int* __restrict__ csr) {
    __shared__ int cnt[256];
    __shared__ int sc[256];
    __shared__ int cur[256];
    int tid = threadIdx.x;
    int b = blockIdx.x;
    int s = bucketBase[b], e = bucketBase[b + 1];
    cnt[tid] = 0;
    __syncthreads();
    for (int idx = s + tid; idx < e; idx += 256)
        atomicAdd(&cnt[ebuf[idx] & 255], 1);
    __syncthreads();
    int c = cnt[tid];
    int pad = (c + 7) & ~7;
    sc[tid] = pad;
    __syncthreads();
    for (int off = 1; off < 256; off <<= 1) {
        int x = sc[tid];
        if (tid >= off) x += sc[tid - off];
        __syncthreads();
        sc[tid] = x;
        __syncthreads();
    }
    int pexcl = sc[tid] - pad;
    int base = s + b * BSLACK + pexcl;   // padded segment start for this node
    int node = b * 256 + tid;
    if (node < N_NODES) {
        offsets[node] = base;
        nbArr[node] = pad >> 3;
    }
    cur[tid] = base;
    __syncthreads();
    for (int idx = s + tid; idx < e; idx += 256) {
        int pk = ebuf[idx];
        int pos = atomicAdd(&cur[pk & 255], 1);
        csr[pos] = (int)((unsigned)pk >> 8);
    }
    __syncthreads();
    int pend = base + pad;
    for (int p2 = cur[tid]; p2 < pend; p2++) csr[p2] = N_NODES;  // sentinel fill (<=7)
}

// ---------------- per-layer compute ----------------

// G[g][row][c] = row-th row of H@W, cols g*16..g*16+15, bf16 (RNE).
// Row N_NODES (sentinel) written as zeros every layer (hs loader zero-fills).
__global__ __launch_bounds__(256) void gemm_k(const float* __restrict__ H,
                                              const float* __restrict__ W,
                                              unsigned short* __restrict__ G) {
    __shared__ float hs[64][128];
    int tid = threadIdx.x;
    int rowBase = blockIdx.x * 64;
    for (int i = tid; i < 64 * 32; i += 256) {
        int r = i >> 5, c4 = i & 31;
        int row = rowBase + r;
        float4 v = make_float4(0.f, 0.f, 0.f, 0.f);
        if (row < N_NODES) v = ((const float4*)(H + (size_t)row * DIM))[c4];
        ((float4*)&hs[r][0])[c4] = v;
    }
    __syncthreads();

    int tx = tid & 31, ty = tid >> 5;
    int c0 = tx * 4, r0 = ty * 8;
    float4 acc[8];
#pragma unroll
    for (int r = 0; r < 8; r++) acc[r] = make_float4(0.f, 0.f, 0.f, 0.f);

#pragma unroll 4
    for (int k = 0; k < DIM; k++) {
        float4 wv = *(const float4*)(W + (size_t)k * DIM + c0);
#pragma unroll
        for (int r = 0; r < 8; r++) {
            float a = hs[r0 + r][k];
            acc[r].x += a * wv.x;
            acc[r].y += a * wv.y;
            acc[r].z += a * wv.z;
            acc[r].w += a * wv.w;
        }
    }
    int gg = c0 >> 4, wc = c0 & 15;
#pragma unroll
    for (int r = 0; r < 8; r++) {
        int row = rowBase + r0 + r;
        if (row <= N_NODES) {   // includes sentinel row (acc==0 there)
            uint2 pk;
            pk.x = rne_bf16(acc[r].x) | (rne_bf16(acc[r].y) << 16);
            pk.y = rne_bf16(acc[r].z) | (rne_bf16(acc[r].w) << 16);
            *(uint2*)(G + ((size_t)gg * GROWS + row) * GCOLS + wc) = pk;
        }
    }
}

__device__ __forceinline__ void accum8(float* acc, uint4 v) {
    acc[0] += bf16lo(v.x); acc[1] += bf16hi(v.x);
    acc[2] += bf16lo(v.y); acc[3] += bf16hi(v.y);
    acc[4] += bf16lo(v.z); acc[5] += bf16hi(v.z);
    acc[6] += bf16lo(v.w); acc[7] += bf16hi(v.w);
}

// Column-group aggregation with padded CSR. Block handles group g = blockIdx&7
// (round-robin block->XCD dispatch pins each 3.2MB G-slice into one XCD's L2 --
// proven: FETCH 362->86 MB). 4 nodes/wave (quarter = lane>>4); per node 16
// lanes: e8 = edge slot (8 edges/batch), h = 16B half-slice. Batch granularity
// 8 (was 32: padding waste 2x -> 1.2x). Sentinel-padded csr removes clamp math;
// 4-deep unroll keeps idx->gather chains overlapped.
__global__ __launch_bounds__(256) void agg_k(const unsigned short* __restrict__ G,
                                             const int* __restrict__ off,
                                             const int* __restrict__ nbArr,
                                             const int* __restrict__ csr,
                                             const float* __restrict__ bias,
                                             const float* __restrict__ epsp,
                                             float* __restrict__ out) {
    int tid = threadIdx.x;
    int lane = tid & 63;
    int wid = tid >> 6;
    int g = blockIdx.x & 7;
    int chunk = blockIdx.x >> 3;
    int quarter = lane >> 4;
    int ql = lane & 15;
    int e8 = ql >> 1;
    int h = ql & 1;
    int node = chunk * 16 + wid * 4 + quarter;
    const unsigned short* Gg = G + (size_t)g * GROWS * GCOLS;
    const unsigned short* GgH = Gg + h * 8;

    float e1 = 1.0f + epsp[0];
    int offA = off[node];
    int mynb = nbArr[node];
    const int* clb = csr + offA + e8;

    // wave-uniform trip count = max batches over the wave's 4 nodes
    int nb = mynb;
    nb = max(nb, __shfl_xor(nb, 16));
    nb = max(nb, __shfl_xor(nb, 32));

    float acc[8] = {0.f, 0.f, 0.f, 0.f, 0.f, 0.f, 0.f, 0.f};

    int b = 0;
    for (; b + 4 <= nb; b += 4) {
        int i0 = clb[0];
        int i1 = clb[8];
        int i2 = clb[16];
        int i3 = clb[24];
        clb += 32;
        i0 = (b     < mynb) ? i0 : N_NODES;
        i1 = (b + 1 < mynb) ? i1 : N_NODES;
        i2 = (b + 2 < mynb) ? i2 : N_NODES;
        i3 = (b + 3 < mynb) ? i3 : N_NODES;
        uint4 g0 = *(const uint4*)(GgH + (size_t)i0 * GCOLS);
        uint4 g1 = *(const uint4*)(GgH + (size_t)i1 * GCOLS);
        uint4 g2 = *(const uint4*)(GgH + (size_t)i2 * GCOLS);
        uint4 g3 = *(const uint4*)(GgH + (size_t)i3 * GCOLS);
        accum8(acc, g0);
        accum8(acc, g1);
        accum8(acc, g2);
        accum8(acc, g3);
    }
    for (; b < nb; b++) {
        int i0 = clb[0];
        clb += 8;
        i0 = (b < mynb) ? i0 : N_NODES;
        uint4 g0 = *(const uint4*)(GgH + (size_t)i0 * GCOLS);
        accum8(acc, g0);
    }

    // butterfly reduce over edge slots (lane bits 1..3); h (bit 0) preserved
#pragma unroll
    for (int j = 0; j < 8; j++) {
        acc[j] += __shfl_xor(acc[j], 2);
        acc[j] += __shfl_xor(acc[j], 4);
        acc[j] += __shfl_xor(acc[j], 8);
    }

    if (e8 == 0) {   // 2 lanes per node: h=0 -> cols 0..7 of group, h=1 -> cols 8..15
        uint4 sv = *(const uint4*)(Gg + (size_t)node * GCOLS + h * 8);
        int colb = g * GCOLS + h * 8;
        float4 b0 = *(const float4*)(bias + colb);
        float4 b1 = *(const float4*)(bias + colb + 4);
        float* op = out + (size_t)node * DIM + colb;
        float4 r0, r1;
        r0.x = acc[0] + e1 * bf16lo(sv.x) + b0.x;
        r0.y = acc[1] + e1 * bf16hi(sv.x) + b0.y;
        r0.z = acc[2] + e1 * bf16lo(sv.y) + b0.z;
        r0.w = acc[3] + e1 * bf16hi(sv.y) + b0.w;
        r1.x = acc[4] + e1 * bf16lo(sv.z) + b1.x;
        r1.y = acc[5] + e1 * bf16hi(sv.z) + b1.y;
        r1.z = acc[6] + e1 * bf16lo(sv.w) + b1.z;
        r1.w = acc[7] + e1 * bf16hi(sv.w) + b1.w;
        *(float4*)op = r0;
        *(float4*)(op + 4) = r1;
    }
}

// ---------------- launch ----------------

extern "C" void kernel_launch(void* const* d_in, const int* in_sizes, int n_in,
                              void* d_out, int out_size, void* d_ws, size_t ws_size,
                              hipStream_t stream) {
    const float* feats = (const float*)d_in[0];
    const int* esrc = (const int*)d_in[1];
    const int* edst = (const int*)d_in[2];
    const float* Wm[3] = {(const float*)d_in[3], (const float*)d_in[6], (const float*)d_in[9]};
    const float* Bv[3] = {(const float*)d_in[4], (const float*)d_in[7], (const float*)d_in[10]};
    const float* Ev[3] = {(const float*)d_in[5], (const float*)d_in[8], (const float*)d_in[11]};
    float* out = (float*)d_out;

    char* ws = (char*)d_ws;
    unsigned short* bufG = (unsigned short*)(ws);        // 25,600,512 B : [8][100001][16] bf16
    int* ebuf       = (int*)(ws + 25600512);             // 12,800,000 B packed (src<<8|dst&255)
    int* csr        = (int*)(ws + 38400512);             // 16,011,264 B padded csr
    int* offsets    = (int*)(ws + 54411776);             //    400,000 B
    int* nbArr      = (int*)(ws + 54811776);             //    400,000 B
    int* bucketTotal= (int*)(ws + 55211776);             //      1,568 B
    int* bucketBase = (int*)(ws + 55213376);             //      1,572 B
    int* bucketCur  = (int*)(ws + 55215040);             //      1,568 B

    // CSR build: bucket counting sort
    hipMemsetAsync(bucketTotal, 0, NBP * sizeof(int), stream);
    bhist_k<<<EB_BLOCKS, 256, 0, stream>>>(edst, bucketTotal);
    bscan_k<<<1, 512, 0, stream>>>(bucketTotal, bucketBase, bucketCur);
    bscatter_k<<<EB_BLOCKS, 256, 0, stream>>>(esrc, edst, bucketCur, ebuf);
    bfinal_k<<<NBUCK, 256, 0, stream>>>(ebuf, bucketBase, offsets, nbArr, csr);

    // 3 GIN layers: g = h @ W  (bufG, bf16, group-major);  h' = (1+eps)g + agg(g) + b
    const float* h = feats;
    for (int l = 0; l < 3; l++) {
        gemm_k<<<(N_NODES + 64) / 64, 256, 0, stream>>>(h, Wm[l], bufG);  // covers sentinel row
        agg_k<<<GRP * (N_NODES / 16), 256, 0, stream>>>(bufG, offsets, nbArr, csr, Bv[l], Ev[l], out);
        h = out;
    }
}

// Round 5
// 711.186 us; speedup vs baseline: 1.1730x; 1.1565x over previous
//
#include <hip/hip_runtime.h>

#define N_NODES 100000
#define N_EDGES 3200000
#define DIM 128
#define GROWS (N_NODES + 1)   // +1: sentinel all-zero row for csr padding
#define NBUCK 391        // ceil(100000/256) buckets of 256 nodes (dst>>8)
#define NBP 392          // padded
#define EB_BLOCKS 782    // ceil(3.2M / 4096) edge blocks (4096 edges/block)
#define BSLACK 2048      // per-bucket csr padding slack (>= 256 nodes * 3)

// ---------------- helpers ----------------

__device__ __forceinline__ unsigned rne_bf16(float f) {
    unsigned u = __builtin_bit_cast(unsigned, f);
    return (u + 0x7FFFu + ((u >> 16) & 1u)) >> 16;
}
__device__ __forceinline__ float bf16lo(unsigned u) {
    return __builtin_bit_cast(float, u << 16);
}
__device__ __forceinline__ float bf16hi(unsigned u) {
    return __builtin_bit_cast(float, u & 0xFFFF0000u);
}

// ---------------- CSR build: bucket counting sort ----------------

// B1: per-block LDS hist of 4096 edges into 392 buckets; 1 global atomic per (block,bucket)
__global__ __launch_bounds__(256) void bhist_k(const int* __restrict__ dst,
                                               int* __restrict__ bucketTotal) {
    __shared__ int h[NBP];
    int tid = threadIdx.x;
    for (int i = tid; i < NBP; i += 256) h[i] = 0;
    __syncthreads();
#pragma unroll
    for (int c = 0; c < 4; c++) {
        int e = blockIdx.x * 4096 + c * 1024 + tid * 4;
        if (e < N_EDGES) {
            int4 d4 = ((const int4*)dst)[e >> 2];
            atomicAdd(&h[d4.x >> 8], 1);
            atomicAdd(&h[d4.y >> 8], 1);
            atomicAdd(&h[d4.z >> 8], 1);
            atomicAdd(&h[d4.w >> 8], 1);
        }
    }
    __syncthreads();
    for (int i = tid; i < NBP; i += 256)
        if (h[i] > 0) atomicAdd(&bucketTotal[i], h[i]);
}

// B2: exclusive scan of 392 bucket totals -> bucketBase[0..392], init cursors
__global__ __launch_bounds__(512) void bscan_k(const int* __restrict__ bucketTotal,
                                               int* __restrict__ bucketBase,
                                               int* __restrict__ bucketCursor) {
    __shared__ int tmp[512];
    int tid = threadIdx.x;
    int v = (tid < NBP) ? bucketTotal[tid] : 0;
    tmp[tid] = v;
    __syncthreads();
    for (int off = 1; off < 512; off <<= 1) {
        int x = tmp[tid];
        if (tid >= off) x += tmp[tid - off];
        __syncthreads();
        tmp[tid] = x;
        __syncthreads();
    }
    if (tid < NBP) {
        int excl = tmp[tid] - v;
        bucketBase[tid] = excl;
        bucketCursor[tid] = excl;
        if (tid == NBP - 1) bucketBase[NBP] = tmp[tid];
    }
}

// B3: re-hist per block, reserve per-bucket runs, scatter PACKED (src<<8 | dst&255)
// into bucket regions (1 int/edge: halves scatter bytes vs int2)
__global__ __launch_bounds__(256) void bscatter_k(const int* __restrict__ src,
                                                  const int* __restrict__ dst,
                                                  int* __restrict__ bucketCursor,
                                                  int* __restrict__ ebuf) {
    __shared__ int h[NBP];
    __shared__ int lcur[NBP];
    int tid = threadIdx.x;
    for (int i = tid; i < NBP; i += 256) h[i] = 0;
    __syncthreads();
#pragma unroll
    for (int c = 0; c < 4; c++) {
        int e = blockIdx.x * 4096 + c * 1024 + tid * 4;
        if (e < N_EDGES) {
            int4 d4 = ((const int4*)dst)[e >> 2];
            atomicAdd(&h[d4.x >> 8], 1);
            atomicAdd(&h[d4.y >> 8], 1);
            atomicAdd(&h[d4.z >> 8], 1);
            atomicAdd(&h[d4.w >> 8], 1);
        }
    }
    __syncthreads();
    for (int i = tid; i < NBP; i += 256)
        lcur[i] = (h[i] > 0) ? atomicAdd(&bucketCursor[i], h[i]) : 0;
    __syncthreads();
#pragma unroll
    for (int c = 0; c < 4; c++) {
        int e = blockIdx.x * 4096 + c * 1024 + tid * 4;
        if (e < N_EDGES) {
            int4 d4 = ((const int4*)dst)[e >> 2];
            int4 s4 = ((const int4*)src)[e >> 2];
            int p0 = atomicAdd(&lcur[d4.x >> 8], 1);
            int p1 = atomicAdd(&lcur[d4.y >> 8], 1);
            int p2 = atomicAdd(&lcur[d4.z >> 8], 1);
            int p3 = atomicAdd(&lcur[d4.w >> 8], 1);
            ebuf[p0] = (s4.x << 8) | (d4.x & 255);
            ebuf[p1] = (s4.y << 8) | (d4.y & 255);
            ebuf[p2] = (s4.z << 8) | (d4.z & 255);
            ebuf[p3] = (s4.w << 8) | (d4.w & 255);
        }
    }
}

// B4: one block per bucket: count, PADDED scan (each node's list padded to mult.
// of 4 with sentinel N_NODES -> branch-free agg loop), rank -> padded csr.
// offsets[node] = padded start; nbArr[node] = #4-edge batches.
__global__ __launch_bounds__(256) void bfinal_k(const int* __restrict__ ebuf,
                                                const int* __restrict__ bucketBase,
                                                int* __restrict__ offsets,
                                                int* __restrict__ nbArr,
                                                int* __restrict__ csr) {
    __shared__ int cnt[256];
    __shared__ int sc[256];
    __shared__ int cur[256];
    int tid = threadIdx.x;
    int b = blockIdx.x;
    int s = bucketBase[b], e = bucketBase[b + 1];
    cnt[tid] = 0;
    __syncthreads();
    for (int idx = s + tid; idx < e; idx += 256)
        atomicAdd(&cnt[ebuf[idx] & 255], 1);
    __syncthreads();
    int c = cnt[tid];
    int pad = (c + 3) & ~3;
    sc[tid] = pad;
    __syncthreads();
    for (int off = 1; off < 256; off <<= 1) {
        int x = sc[tid];
        if (tid >= off) x += sc[tid - off];
        __syncthreads();
        sc[tid] = x;
        __syncthreads();
    }
    int pexcl = sc[tid] - pad;
    int base = s + b * BSLACK + pexcl;   // padded segment start for this node
    int node = b * 256 + tid;
    if (node < N_NODES) {
        offsets[node] = base;
        nbArr[node] = pad >> 2;
    }
    cur[tid] = base;
    __syncthreads();
    for (int idx = s + tid; idx < e; idx += 256) {
        int pk = ebuf[idx];
        int pos = atomicAdd(&cur[pk & 255], 1);
        csr[pos] = (int)((unsigned)pk >> 8);
    }
    __syncthreads();
    int pend = base + pad;
    for (int p2 = cur[tid]; p2 < pend; p2++) csr[p2] = N_NODES;  // sentinel fill (<=3)
}

// ---------------- per-layer compute ----------------

// G[row][c] = (H@W)[row][c], bf16 (RNE), plain [100001][128] layout (grouped
// layout reverted: it halved gather line-utilization and the request tax ate
// the L2-residency win). Row N_NODES = sentinel zeros.
// Inner loop: round-0 form (proven; k+=4 variant regressed).
__global__ __launch_bounds__(256) void gemm_k(const float* __restrict__ H,
                                              const float* __restrict__ W,
                                              unsigned short* __restrict__ G) {
    __shared__ float hs[64][128];
    int tid = threadIdx.x;
    int rowBase = blockIdx.x * 64;
    for (int i = tid; i < 64 * 32; i += 256) {
        int r = i >> 5, c4 = i & 31;
        int row = rowBase + r;
        float4 v = make_float4(0.f, 0.f, 0.f, 0.f);
        if (row < N_NODES) v = ((const float4*)(H + (size_t)row * DIM))[c4];
        ((float4*)&hs[r][0])[c4] = v;
    }
    __syncthreads();

    int tx = tid & 31, ty = tid >> 5;
    int c0 = tx * 4, r0 = ty * 8;
    float4 acc[8];
#pragma unroll
    for (int r = 0; r < 8; r++) acc[r] = make_float4(0.f, 0.f, 0.f, 0.f);

#pragma unroll 4
    for (int k = 0; k < DIM; k++) {
        float4 wv = *(const float4*)(W + (size_t)k * DIM + c0);
#pragma unroll
        for (int r = 0; r < 8; r++) {
            float a = hs[r0 + r][k];
            acc[r].x += a * wv.x;
            acc[r].y += a * wv.y;
            acc[r].z += a * wv.z;
            acc[r].w += a * wv.w;
        }
    }
#pragma unroll
    for (int r = 0; r < 8; r++) {
        int row = rowBase + r0 + r;
        if (row <= N_NODES) {   // includes sentinel row (hs zero-filled -> acc==0)
            uint2 pk;
            pk.x = rne_bf16(acc[r].x) | (rne_bf16(acc[r].y) << 16);
            pk.y = rne_bf16(acc[r].z) | (rne_bf16(acc[r].w) << 16);
            *(uint2*)(G + (size_t)row * DIM + c0) = pk;
        }
    }
}

__device__ __forceinline__ void accum8(float* acc, uint4 v) {
    acc[0] += bf16lo(v.x); acc[1] += bf16hi(v.x);
    acc[2] += bf16lo(v.y); acc[3] += bf16hi(v.y);
    acc[4] += bf16lo(v.z); acc[5] += bf16hi(v.z);
    acc[6] += bf16lo(v.w); acc[7] += bf16hi(v.w);
}

// Ungrouped full-row gather (proven 112us structure) + padded CSR polish.
// ONE node per wave (no wave-max padding waste); quarter = lane>>4 picks the
// edge of a 4-edge batch, q = lane&15 picks the 16B slice of the 256B row --
// every gather instr moves 4 full rows = 16 fully-utilized 64B lines.
// Sentinel-padded csr (pad slots -> all-zero row N_NODES): no validity VALU,
// no tail branches. 4-batch unroll = 16 edges in flight.
__global__ __launch_bounds__(256) void agg_k(const unsigned short* __restrict__ G,
                                             const int* __restrict__ off,
                                             const int* __restrict__ nbArr,
                                             const int* __restrict__ csr,
                                             const float* __restrict__ bias,
                                             const float* __restrict__ epsp,
                                             float* __restrict__ out) {
    int tid = threadIdx.x;
    int lane = tid & 63;
    int node = blockIdx.x * 4 + (tid >> 6);
    int quarter = lane >> 4;   // 0..3: edge within the batch
    int q = lane & 15;         // 0..15: 16B slice (cols 8q..8q+7)
    float e1 = 1.0f + epsp[0];

    int offA = off[node];
    int nb = nbArr[node];
    const int* clb = csr + offA + quarter;

    float acc[8] = {0.f, 0.f, 0.f, 0.f, 0.f, 0.f, 0.f, 0.f};

    int b = 0;
    for (; b + 4 <= nb; b += 4) {
        int i0 = clb[0];
        int i1 = clb[4];
        int i2 = clb[8];
        int i3 = clb[12];
        clb += 16;
        uint4 g0 = *(const uint4*)(G + (size_t)i0 * DIM + q * 8);
        uint4 g1 = *(const uint4*)(G + (size_t)i1 * DIM + q * 8);
        uint4 g2 = *(const uint4*)(G + (size_t)i2 * DIM + q * 8);
        uint4 g3 = *(const uint4*)(G + (size_t)i3 * DIM + q * 8);
        accum8(acc, g0);
        accum8(acc, g1);
        accum8(acc, g2);
        accum8(acc, g3);
    }
    for (; b < nb; b++) {
        int i0 = clb[0];
        clb += 4;
        uint4 g0 = *(const uint4*)(G + (size_t)i0 * DIM + q * 8);
        accum8(acc, g0);
    }

    // reduce the 4 edge-copies of each column slice (lane bits 4,5)
#pragma unroll
    for (int j = 0; j < 8; j++) {
        acc[j] += __shfl_xor(acc[j], 16);
        acc[j] += __shfl_xor(acc[j], 32);
    }

    if (quarter == 0) {   // 16 lanes write the node's 128 cols (8 each)
        uint4 sv = *(const uint4*)(G + (size_t)node * DIM + q * 8);
        float4 b0 = *(const float4*)(bias + q * 8);
        float4 b1 = *(const float4*)(bias + q * 8 + 4);
        float* op = out + (size_t)node * DIM + q * 8;
        float4 r0, r1;
        r0.x = acc[0] + e1 * bf16lo(sv.x) + b0.x;
        r0.y = acc[1] + e1 * bf16hi(sv.x) + b0.y;
        r0.z = acc[2] + e1 * bf16lo(sv.y) + b0.z;
        r0.w = acc[3] + e1 * bf16hi(sv.y) + b0.w;
        r1.x = acc[4] + e1 * bf16lo(sv.z) + b1.x;
        r1.y = acc[5] + e1 * bf16hi(sv.z) + b1.y;
        r1.z = acc[6] + e1 * bf16lo(sv.w) + b1.z;
        r1.w = acc[7] + e1 * bf16hi(sv.w) + b1.w;
        *(float4*)op = r0;
        *(float4*)(op + 4) = r1;
    }
}

// ---------------- launch ----------------

extern "C" void kernel_launch(void* const* d_in, const int* in_sizes, int n_in,
                              void* d_out, int out_size, void* d_ws, size_t ws_size,
                              hipStream_t stream) {
    const float* feats = (const float*)d_in[0];
    const int* esrc = (const int*)d_in[1];
    const int* edst = (const int*)d_in[2];
    const float* Wm[3] = {(const float*)d_in[3], (const float*)d_in[6], (const float*)d_in[9]};
    const float* Bv[3] = {(const float*)d_in[4], (const float*)d_in[7], (const float*)d_in[10]};
    const float* Ev[3] = {(const float*)d_in[5], (const float*)d_in[8], (const float*)d_in[11]};
    float* out = (float*)d_out;

    char* ws = (char*)d_ws;
    unsigned short* bufG = (unsigned short*)(ws);        // 25,600,256 B : [100001][128] bf16
    int* ebuf       = (int*)(ws + 25600512);             // 12,800,000 B packed (src<<8|dst&255)
    int* csr        = (int*)(ws + 38400512);             // 16,011,264 B padded csr
    int* offsets    = (int*)(ws + 54411776);             //    400,000 B
    int* nbArr      = (int*)(ws + 54811776);             //    400,000 B
    int* bucketTotal= (int*)(ws + 55211776);             //      1,568 B
    int* bucketBase = (int*)(ws + 55213376);             //      1,572 B
    int* bucketCur  = (int*)(ws + 55215040);             //      1,568 B

    // CSR build: bucket counting sort
    hipMemsetAsync(bucketTotal, 0, NBP * sizeof(int), stream);
    bhist_k<<<EB_BLOCKS, 256, 0, stream>>>(edst, bucketTotal);
    bscan_k<<<1, 512, 0, stream>>>(bucketTotal, bucketBase, bucketCur);
    bscatter_k<<<EB_BLOCKS, 256, 0, stream>>>(esrc, edst, bucketCur, ebuf);
    bfinal_k<<<NBUCK, 256, 0, stream>>>(ebuf, bucketBase, offsets, nbArr, csr);

    // 3 GIN layers: g = h @ W  (bufG, bf16);  h' = (1+eps)g + agg(g) + b  (d_out, f32)
    const float* h = feats;
    for (int l = 0; l < 3; l++) {
        gemm_k<<<(N_NODES + 64) / 64, 256, 0, stream>>>(h, Wm[l], bufG);  // covers sentinel row
        agg_k<<<N_NODES / 4, 256, 0, stream>>>(bufG, offsets, nbArr, csr, Bv[l], Ev[l], out);
        h = out;
    }
}

// Round 6
// 708.772 us; speedup vs baseline: 1.1770x; 1.0034x over previous
//
#include <hip/hip_runtime.h>

#define N_NODES 100000
#define N_EDGES 3200000
#define DIM 128
#define GROWS (N_NODES + 1)   // +1: sentinel all-zero row for csr padding
#define NBUCK 391        // ceil(100000/256) buckets of 256 nodes (dst>>8)
#define NBP 392          // padded
#define EB_BLOCKS 782    // ceil(3.2M / 4096) edge blocks (4096 edges/block)
#define BSLACK 2048      // per-bucket csr padding slack (>= 256 nodes * 3)
#define MAXB 9216        // LDS staging cap for one bucket's edges (mean 8192, +11 sigma)

// ---------------- helpers ----------------

__device__ __forceinline__ unsigned rne_bf16(float f) {
    unsigned u = __builtin_bit_cast(unsigned, f);
    return (u + 0x7FFFu + ((u >> 16) & 1u)) >> 16;
}
__device__ __forceinline__ float bf16lo(unsigned u) {
    return __builtin_bit_cast(float, u << 16);
}
__device__ __forceinline__ float bf16hi(unsigned u) {
    return __builtin_bit_cast(float, u & 0xFFFF0000u);
}

// ---------------- CSR build: bucket counting sort ----------------

// B1: per-block LDS hist of 4096 edges into 392 buckets; 1 global atomic per
// (block,bucket). Also SAVES the per-block histogram (bhArr) so bscatter
// doesn't have to redo it (removes 12.8M LDS atomics + a 12.8MB edge re-read).
__global__ __launch_bounds__(256) void bhist_k(const int* __restrict__ dst,
                                               int* __restrict__ bucketTotal,
                                               int* __restrict__ bhArr) {
    __shared__ int h[NBP];
    int tid = threadIdx.x;
    for (int i = tid; i < NBP; i += 256) h[i] = 0;
    __syncthreads();
#pragma unroll
    for (int c = 0; c < 4; c++) {
        int e = blockIdx.x * 4096 + c * 1024 + tid * 4;
        if (e < N_EDGES) {
            int4 d4 = ((const int4*)dst)[e >> 2];
            atomicAdd(&h[d4.x >> 8], 1);
            atomicAdd(&h[d4.y >> 8], 1);
            atomicAdd(&h[d4.z >> 8], 1);
            atomicAdd(&h[d4.w >> 8], 1);
        }
    }
    __syncthreads();
    for (int i = tid; i < NBP; i += 256) {
        int v = h[i];
        bhArr[blockIdx.x * NBP + i] = v;
        if (v > 0) atomicAdd(&bucketTotal[i], v);
    }
}

// B2: exclusive scan of 392 bucket totals -> bucketBase[0..392], init cursors
__global__ __launch_bounds__(512) void bscan_k(const int* __restrict__ bucketTotal,
                                               int* __restrict__ bucketBase,
                                               int* __restrict__ bucketCursor) {
    __shared__ int tmp[512];
    int tid = threadIdx.x;
    int v = (tid < NBP) ? bucketTotal[tid] : 0;
    tmp[tid] = v;
    __syncthreads();
    for (int off = 1; off < 512; off <<= 1) {
        int x = tmp[tid];
        if (tid >= off) x += tmp[tid - off];
        __syncthreads();
        tmp[tid] = x;
        __syncthreads();
    }
    if (tid < NBP) {
        int excl = tmp[tid] - v;
        bucketBase[tid] = excl;
        bucketCursor[tid] = excl;
        if (tid == NBP - 1) bucketBase[NBP] = tmp[tid];
    }
}

// B3: load saved per-block histogram, reserve per-bucket runs, scatter PACKED
// (src<<8 | dst&255) into bucket regions. Single edge pass (hist pass fused away).
__global__ __launch_bounds__(256) void bscatter_k(const int* __restrict__ src,
                                                  const int* __restrict__ dst,
                                                  const int* __restrict__ bhArr,
                                                  int* __restrict__ bucketCursor,
                                                  int* __restrict__ ebuf) {
    __shared__ int lcur[NBP];
    int tid = threadIdx.x;
    for (int i = tid; i < NBP; i += 256) {
        int v = bhArr[blockIdx.x * NBP + i];
        lcur[i] = (v > 0) ? atomicAdd(&bucketCursor[i], v) : 0;
    }
    __syncthreads();
#pragma unroll
    for (int c = 0; c < 4; c++) {
        int e = blockIdx.x * 4096 + c * 1024 + tid * 4;
        if (e < N_EDGES) {
            int4 d4 = ((const int4*)dst)[e >> 2];
            int4 s4 = ((const int4*)src)[e >> 2];
            int p0 = atomicAdd(&lcur[d4.x >> 8], 1);
            int p1 = atomicAdd(&lcur[d4.y >> 8], 1);
            int p2 = atomicAdd(&lcur[d4.z >> 8], 1);
            int p3 = atomicAdd(&lcur[d4.w >> 8], 1);
            ebuf[p0] = (s4.x << 8) | (d4.x & 255);
            ebuf[p1] = (s4.y << 8) | (d4.y & 255);
            ebuf[p2] = (s4.z << 8) | (d4.z & 255);
            ebuf[p3] = (s4.w << 8) | (d4.w & 255);
        }
    }
}

// B4: one block per bucket: stage bucket's edges in LDS (one global read, was
// two), count, PADDED scan (pad to mult. of 4 with sentinel), rank -> padded csr.
// offsets[node] = padded start; nbArr[node] = #4-edge batches.
__global__ __launch_bounds__(256) void bfinal_k(const int* __restrict__ ebuf,
                                                const int* __restrict__ bucketBase,
                                                int* __restrict__ offsets,
                                                int* __restrict__ nbArr,
                                                int* __restrict__ csr) {
    __shared__ int eb[MAXB];
    __shared__ int cnt[256];
    __shared__ int sc[256];
    __shared__ int cur[256];
    int tid = threadIdx.x;
    int b = blockIdx.x;
    int s = bucketBase[b], e = bucketBase[b + 1];
    int m = e - s;
    bool fits = (m <= MAXB);
    cnt[tid] = 0;
    __syncthreads();
    if (fits) {
        for (int i = tid; i < m; i += 256) {
            int pk = ebuf[s + i];
            eb[i] = pk;
            atomicAdd(&cnt[pk & 255], 1);
        }
    } else {   // fallback (statistically never: m ~ 8192 +- 90)
        for (int i = tid; i < m; i += 256)
            atomicAdd(&cnt[ebuf[s + i] & 255], 1);
    }
    __syncthreads();
    int c = cnt[tid];
    int pad = (c + 3) & ~3;
    sc[tid] = pad;
    __syncthreads();
    for (int off = 1; off < 256; off <<= 1) {
        int x = sc[tid];
        if (tid >= off) x += sc[tid - off];
        __syncthreads();
        sc[tid] = x;
        __syncthreads();
    }
    int pexcl = sc[tid] - pad;
    int base = s + b * BSLACK + pexcl;   // padded segment start for this node
    int node = b * 256 + tid;
    if (node < N_NODES) {
        offsets[node] = base;
        nbArr[node] = pad >> 2;
    }
    cur[tid] = base;
    __syncthreads();
    if (fits) {
        for (int i = tid; i < m; i += 256) {
            int pk = eb[i];
            int pos = atomicAdd(&cur[pk & 255], 1);
            csr[pos] = (int)((unsigned)pk >> 8);
        }
    } else {
        for (int i = tid; i < m; i += 256) {
            int pk = ebuf[s + i];
            int pos = atomicAdd(&cur[pk & 255], 1);
            csr[pos] = (int)((unsigned)pk >> 8);
        }
    }
    __syncthreads();
    int pend = base + pad;
    for (int p2 = cur[tid]; p2 < pend; p2++) csr[p2] = N_NODES;  // sentinel fill (<=3)
}

// ---------------- per-layer compute ----------------

// G[row][c] = (H@W)[row][c], bf16 (RNE), plain [100001][128] layout. Row
// N_NODES = sentinel zeros. Inner loop: round-0 form (proven; k+=4 regressed).
__global__ __launch_bounds__(256) void gemm_k(const float* __restrict__ H,
                                              const float* __restrict__ W,
                                              unsigned short* __restrict__ G) {
    __shared__ float hs[64][128];
    int tid = threadIdx.x;
    int rowBase = blockIdx.x * 64;
    for (int i = tid; i < 64 * 32; i += 256) {
        int r = i >> 5, c4 = i & 31;
        int row = rowBase + r;
        float4 v = make_float4(0.f, 0.f, 0.f, 0.f);
        if (row < N_NODES) v = ((const float4*)(H + (size_t)row * DIM))[c4];
        ((float4*)&hs[r][0])[c4] = v;
    }
    __syncthreads();

    int tx = tid & 31, ty = tid >> 5;
    int c0 = tx * 4, r0 = ty * 8;
    float4 acc[8];
#pragma unroll
    for (int r = 0; r < 8; r++) acc[r] = make_float4(0.f, 0.f, 0.f, 0.f);

#pragma unroll 4
    for (int k = 0; k < DIM; k++) {
        float4 wv = *(const float4*)(W + (size_t)k * DIM + c0);
#pragma unroll
        for (int r = 0; r < 8; r++) {
            float a = hs[r0 + r][k];
            acc[r].x += a * wv.x;
            acc[r].y += a * wv.y;
            acc[r].z += a * wv.z;
            acc[r].w += a * wv.w;
        }
    }
#pragma unroll
    for (int r = 0; r < 8; r++) {
        int row = rowBase + r0 + r;
        if (row <= N_NODES) {   // includes sentinel row (hs zero-filled -> acc==0)
            uint2 pk;
            pk.x = rne_bf16(acc[r].x) | (rne_bf16(acc[r].y) << 16);
            pk.y = rne_bf16(acc[r].z) | (rne_bf16(acc[r].w) << 16);
            *(uint2*)(G + (size_t)row * DIM + c0) = pk;
        }
    }
}

__device__ __forceinline__ void accum8(float* acc, uint4 v) {
    acc[0] += bf16lo(v.x); acc[1] += bf16hi(v.x);
    acc[2] += bf16lo(v.y); acc[3] += bf16hi(v.y);
    acc[4] += bf16lo(v.z); acc[5] += bf16hi(v.z);
    acc[6] += bf16lo(v.w); acc[7] += bf16hi(v.w);
}

// Ungrouped full-row gather (structural floor ~109us: dur = max(12.8M line-req
// / 168K/us, FETCH / 3.3TB/s) -- model retro-predicts rounds 1/3/4/5). FROZEN.
// ONE node per wave; quarter = lane>>4 picks the edge of a 4-edge batch,
// q = lane&15 picks the 16B slice of the 256B row; sentinel-padded csr ->
// branch-free loop; 4-batch unroll = 16 edges in flight.
__global__ __launch_bounds__(256) void agg_k(const unsigned short* __restrict__ G,
                                             const int* __restrict__ off,
                                             const int* __restrict__ nbArr,
                                             const int* __restrict__ csr,
                                             const float* __restrict__ bias,
                                             const float* __restrict__ epsp,
                                             float* __restrict__ out) {
    int tid = threadIdx.x;
    int lane = tid & 63;
    int node = blockIdx.x * 4 + (tid >> 6);
    int quarter = lane >> 4;   // 0..3: edge within the batch
    int q = lane & 15;         // 0..15: 16B slice (cols 8q..8q+7)
    float e1 = 1.0f + epsp[0];

    int offA = off[node];
    int nb = nbArr[node];
    const int* clb = csr + offA + quarter;

    float acc[8] = {0.f, 0.f, 0.f, 0.f, 0.f, 0.f, 0.f, 0.f};

    int b = 0;
    for (; b + 4 <= nb; b += 4) {
        int i0 = clb[0];
        int i1 = clb[4];
        int i2 = clb[8];
        int i3 = clb[12];
        clb += 16;
        uint4 g0 = *(const uint4*)(G + (size_t)i0 * DIM + q * 8);
        uint4 g1 = *(const uint4*)(G + (size_t)i1 * DIM + q * 8);
        uint4 g2 = *(const uint4*)(G + (size_t)i2 * DIM + q * 8);
        uint4 g3 = *(const uint4*)(G + (size_t)i3 * DIM + q * 8);
        accum8(acc, g0);
        accum8(acc, g1);
        accum8(acc, g2);
        accum8(acc, g3);
    }
    for (; b < nb; b++) {
        int i0 = clb[0];
        clb += 4;
        uint4 g0 = *(const uint4*)(G + (size_t)i0 * DIM + q * 8);
        accum8(acc, g0);
    }

    // reduce the 4 edge-copies of each column slice (lane bits 4,5)
#pragma unroll
    for (int j = 0; j < 8; j++) {
        acc[j] += __shfl_xor(acc[j], 16);
        acc[j] += __shfl_xor(acc[j], 32);
    }

    if (quarter == 0) {   // 16 lanes write the node's 128 cols (8 each)
        uint4 sv = *(const uint4*)(G + (size_t)node * DIM + q * 8);
        float4 b0 = *(const float4*)(bias + q * 8);
        float4 b1 = *(const float4*)(bias + q * 8 + 4);
        float* op = out + (size_t)node * DIM + q * 8;
        float4 r0, r1;
        r0.x = acc[0] + e1 * bf16lo(sv.x) + b0.x;
        r0.y = acc[1] + e1 * bf16hi(sv.x) + b0.y;
        r0.z = acc[2] + e1 * bf16lo(sv.y) + b0.z;
        r0.w = acc[3] + e1 * bf16hi(sv.y) + b0.w;
        r1.x = acc[4] + e1 * bf16lo(sv.z) + b1.x;
        r1.y = acc[5] + e1 * bf16hi(sv.z) + b1.y;
        r1.z = acc[6] + e1 * bf16lo(sv.w) + b1.z;
        r1.w = acc[7] + e1 * bf16hi(sv.w) + b1.w;
        *(float4*)op = r0;
        *(float4*)(op + 4) = r1;
    }
}

// ---------------- launch ----------------

extern "C" void kernel_launch(void* const* d_in, const int* in_sizes, int n_in,
                              void* d_out, int out_size, void* d_ws, size_t ws_size,
                              hipStream_t stream) {
    const float* feats = (const float*)d_in[0];
    const int* esrc = (const int*)d_in[1];
    const int* edst = (const int*)d_in[2];
    const float* Wm[3] = {(const float*)d_in[3], (const float*)d_in[6], (const float*)d_in[9]};
    const float* Bv[3] = {(const float*)d_in[4], (const float*)d_in[7], (const float*)d_in[10]};
    const float* Ev[3] = {(const float*)d_in[5], (const float*)d_in[8], (const float*)d_in[11]};
    float* out = (float*)d_out;

    char* ws = (char*)d_ws;
    unsigned short* bufG = (unsigned short*)(ws);        // 25,600,256 B : [100001][128] bf16
    int* ebuf       = (int*)(ws + 25600512);             // 12,800,000 B packed (src<<8|dst&255)
    int* csr        = (int*)(ws + 38400512);             // 16,003,072 B padded csr
    int* offsets    = (int*)(ws + 54411776);             //    400,000 B
    int* nbArr      = (int*)(ws + 54811776);             //    400,000 B
    int* bucketTotal= (int*)(ws + 55211776);             //      1,568 B
    int* bucketBase = (int*)(ws + 55213376);             //      1,572 B
    int* bucketCur  = (int*)(ws + 55215040);             //      1,568 B
    int* bhArr      = (int*)(ws + 55216640);             //  1,226,176 B per-block bucket hists

    // CSR build: bucket counting sort
    hipMemsetAsync(bucketTotal, 0, NBP * sizeof(int), stream);
    bhist_k<<<EB_BLOCKS, 256, 0, stream>>>(edst, bucketTotal, bhArr);
    bscan_k<<<1, 512, 0, stream>>>(bucketTotal, bucketBase, bucketCur);
    bscatter_k<<<EB_BLOCKS, 256, 0, stream>>>(esrc, edst, bhArr, bucketCur, ebuf);
    bfinal_k<<<NBUCK, 256, 0, stream>>>(ebuf, bucketBase, offsets, nbArr, csr);

    // 3 GIN layers: g = h @ W  (bufG, bf16);  h' = (1+eps)g + agg(g) + b  (d_out, f32)
    const float* h = feats;
    for (int l = 0; l < 3; l++) {
        gemm_k<<<(N_NODES + 64) / 64, 256, 0, stream>>>(h, Wm[l], bufG);  // covers sentinel row
        agg_k<<<N_NODES / 4, 256, 0, stream>>>(bufG, offsets, nbArr, csr, Bv[l], Ev[l], out);
        h = out;
    }
}

// Round 7
// 673.776 us; speedup vs baseline: 1.2381x; 1.0519x over previous
//
#include <hip/hip_runtime.h>

#define N_NODES 100000
#define N_EDGES 3200000
#define DIM 128
#define GROWS (N_NODES + 1)   // +1: sentinel all-zero row for csr padding
#define NBUCK 391        // ceil(100000/256) buckets of 256 nodes (dst>>8)
#define NBP 392          // padded
#define EB_BLOCKS 782    // ceil(3.2M / 4096) edge blocks (4096 edges/block)
#define BSLACK 2048      // per-bucket csr padding slack (>= 256 nodes * 3)
#define MAXPAD 9984      // LDS cap for one bucket's PADDED csr segment (mean ~8.6K, +15 sigma)

// ---------------- helpers ----------------

__device__ __forceinline__ unsigned rne_bf16(float f) {
    unsigned u = __builtin_bit_cast(unsigned, f);
    return (u + 0x7FFFu + ((u >> 16) & 1u)) >> 16;
}
__device__ __forceinline__ float bf16lo(unsigned u) {
    return __builtin_bit_cast(float, u << 16);
}
__device__ __forceinline__ float bf16hi(unsigned u) {
    return __builtin_bit_cast(float, u & 0xFFFF0000u);
}

// ---------------- CSR build: bucket counting sort ----------------
// Round-6 lesson: the duplicate *passes* were nearly free; the real CSR cost
// model is per-lane SCATTERED 4B stores (64 line-requests per wave-store,
// 12.8M per stage ~= 75-100us each at the ~168K req/us ceiling). This round
// de-scatters both store stages via LDS reordering; global store SETS unchanged.

// B1: per-block LDS hist of 4096 edges into 392 buckets; saves per-block hist
// (bhArr) for bscatter; 1 global atomic per (block,bucket).
__global__ __launch_bounds__(256) void bhist_k(const int* __restrict__ dst,
                                               int* __restrict__ bucketTotal,
                                               int* __restrict__ bhArr) {
    __shared__ int h[NBP];
    int tid = threadIdx.x;
    for (int i = tid; i < NBP; i += 256) h[i] = 0;
    __syncthreads();
#pragma unroll
    for (int c = 0; c < 4; c++) {
        int e = blockIdx.x * 4096 + c * 1024 + tid * 4;
        if (e < N_EDGES) {
            int4 d4 = ((const int4*)dst)[e >> 2];
            atomicAdd(&h[d4.x >> 8], 1);
            atomicAdd(&h[d4.y >> 8], 1);
            atomicAdd(&h[d4.z >> 8], 1);
            atomicAdd(&h[d4.w >> 8], 1);
        }
    }
    __syncthreads();
    for (int i = tid; i < NBP; i += 256) {
        int v = h[i];
        bhArr[blockIdx.x * NBP + i] = v;
        if (v > 0) atomicAdd(&bucketTotal[i], v);
    }
}

// B2: exclusive scan of 392 bucket totals -> bucketBase[0..392], init cursors
__global__ __launch_bounds__(512) void bscan_k(const int* __restrict__ bucketTotal,
                                               int* __restrict__ bucketBase,
                                               int* __restrict__ bucketCursor) {
    __shared__ int tmp[512];
    int tid = threadIdx.x;
    int v = (tid < NBP) ? bucketTotal[tid] : 0;
    tmp[tid] = v;
    __syncthreads();
    for (int off = 1; off < 512; off <<= 1) {
        int x = tmp[tid];
        if (tid >= off) x += tmp[tid - off];
        __syncthreads();
        tmp[tid] = x;
        __syncthreads();
    }
    if (tid < NBP) {
        int excl = tmp[tid] - v;
        bucketBase[tid] = excl;
        bucketCursor[tid] = excl;
        if (tid == NBP - 1) bucketBase[NBP] = tmp[tid];
    }
}

// B3 (512 thr): reserve per-bucket runs from saved hist, LDS-SORT the block's
// 4096 edges by bucket (prefix scan + LDS cursors), precompute each slot's
// global address, then write out in sorted order -> consecutive lanes write
// consecutive addresses within bucket runs (HW-coalesced, ~7x fewer line-req).
__global__ __launch_bounds__(512) void bscatter_k(const int* __restrict__ src,
                                                  const int* __restrict__ dst,
                                                  const int* __restrict__ bhArr,
                                                  int* __restrict__ bucketCursor,
                                                  int* __restrict__ ebuf) {
    __shared__ int lcur0[NBP];    // global base of this block's run per bucket
    __shared__ int pexc[NBP];     // exclusive LDS prefix per bucket
    __shared__ int lofs[NBP];     // LDS scatter cursor per bucket
    __shared__ int pfx[512];
    __shared__ int sortedv[4096];
    __shared__ int gaddr[4096];
    int tid = threadIdx.x;
    int bid = blockIdx.x;
    int v = 0;
    if (tid < NBP) {
        v = bhArr[bid * NBP + tid];
        lcur0[tid] = (v > 0) ? atomicAdd(&bucketCursor[tid], v) : 0;
    }
    pfx[tid] = v;
    __syncthreads();
    for (int off = 1; off < 512; off <<= 1) {
        int x = pfx[tid];
        if (tid >= off) x += pfx[tid - off];
        __syncthreads();
        pfx[tid] = x;
        __syncthreads();
    }
    if (tid < NBP) {
        int ex = pfx[tid] - v;
        pexc[tid] = ex;
        lofs[tid] = ex;
    }
    __syncthreads();
#pragma unroll
    for (int c = 0; c < 2; c++) {
        int e = bid * 4096 + c * 2048 + tid * 4;
        if (e < N_EDGES) {
            int4 d4 = ((const int4*)dst)[e >> 2];
            int4 s4 = ((const int4*)src)[e >> 2];
            int b0 = d4.x >> 8, b1 = d4.y >> 8, b2 = d4.z >> 8, b3 = d4.w >> 8;
            int t0 = atomicAdd(&lofs[b0], 1);
            int t1 = atomicAdd(&lofs[b1], 1);
            int t2 = atomicAdd(&lofs[b2], 1);
            int t3 = atomicAdd(&lofs[b3], 1);
            sortedv[t0] = (s4.x << 8) | (d4.x & 255);
            sortedv[t1] = (s4.y << 8) | (d4.y & 255);
            sortedv[t2] = (s4.z << 8) | (d4.z & 255);
            sortedv[t3] = (s4.w << 8) | (d4.w & 255);
            gaddr[t0] = lcur0[b0] + (t0 - pexc[b0]);
            gaddr[t1] = lcur0[b1] + (t1 - pexc[b1]);
            gaddr[t2] = lcur0[b2] + (t2 - pexc[b2]);
            gaddr[t3] = lcur0[b3] + (t3 - pexc[b3]);
        }
    }
    __syncthreads();
    int totalE = min(4096, N_EDGES - bid * 4096);
    for (int j = tid; j < totalE; j += 512)
        ebuf[gaddr[j]] = sortedv[j];
}

// B4: one block per bucket: count, PADDED scan, rank into an LDS image of the
// bucket's entire padded csr segment (sentinel-prefilled), then stream the
// segment out fully CONTIGUOUS (was: 12.8M scattered 4B stores).
// offsets[node] = padded start; nbArr[node] = #4-edge batches.
__global__ __launch_bounds__(256) void bfinal_k(const int* __restrict__ ebuf,
                                                const int* __restrict__ bucketBase,
                                                int* __restrict__ offsets,
                                                int* __restrict__ nbArr,
                                                int* __restrict__ csr) {
    __shared__ int srt[MAXPAD];
    __shared__ int cnt[256];
    __shared__ int sc[256];
    __shared__ int cur[256];
    int tid = threadIdx.x;
    int b = blockIdx.x;
    int s = bucketBase[b], e = bucketBase[b + 1];
    int m = e - s;
    cnt[tid] = 0;
    __syncthreads();
    for (int i = tid; i < m; i += 256)
        atomicAdd(&cnt[ebuf[s + i] & 255], 1);
    __syncthreads();
    int c = cnt[tid];
    int pad = (c + 3) & ~3;
    sc[tid] = pad;
    __syncthreads();
    for (int off = 1; off < 256; off <<= 1) {
        int x = sc[tid];
        if (tid >= off) x += sc[tid - off];
        __syncthreads();
        sc[tid] = x;
        __syncthreads();
    }
    int pexcl = sc[tid] - pad;
    int gbase = s + b * BSLACK;
    int node = b * 256 + tid;
    if (node < N_NODES) {
        offsets[node] = gbase + pexcl;
        nbArr[node] = pad >> 2;
    }
    cur[tid] = pexcl;      // LDS-local cursor
    __syncthreads();
    int padTot = sc[255];
    if (padTot <= MAXPAD) {
        for (int j = tid; j < padTot; j += 256) srt[j] = N_NODES;  // sentinel prefill
        __syncthreads();
        for (int i = tid; i < m; i += 256) {
            int pk = ebuf[s + i];
            int pos = atomicAdd(&cur[pk & 255], 1);
            srt[pos] = (int)((unsigned)pk >> 8);       // LDS scatter (cheap)
        }
        __syncthreads();
        for (int j = tid; j < padTot; j += 256)        // contiguous global stream-out
            csr[gbase + j] = srt[j];
    } else {   // fallback (statistically never): old scattered path
        for (int i = tid; i < m; i += 256) {
            int pk = ebuf[s + i];
            int pos = atomicAdd(&cur[pk & 255], 1);
            csr[gbase + pos] = (int)((unsigned)pk >> 8);
        }
        __syncthreads();
        int pend = pexcl + pad;
        for (int p2 = cur[tid]; p2 < pend; p2++) csr[gbase + p2] = N_NODES;
    }
}

// ---------------- per-layer compute ----------------

// G[row][c] = (H@W)[row][c], bf16 (RNE), plain [100001][128] layout. Row
// N_NODES = sentinel zeros. Inner loop: round-0 form (proven; k+=4 regressed).
__global__ __launch_bounds__(256) void gemm_k(const float* __restrict__ H,
                                              const float* __restrict__ W,
                                              unsigned short* __restrict__ G) {
    __shared__ float hs[64][128];
    int tid = threadIdx.x;
    int rowBase = blockIdx.x * 64;
    for (int i = tid; i < 64 * 32; i += 256) {
        int r = i >> 5, c4 = i & 31;
        int row = rowBase + r;
        float4 v = make_float4(0.f, 0.f, 0.f, 0.f);
        if (row < N_NODES) v = ((const float4*)(H + (size_t)row * DIM))[c4];
        ((float4*)&hs[r][0])[c4] = v;
    }
    __syncthreads();

    int tx = tid & 31, ty = tid >> 5;
    int c0 = tx * 4, r0 = ty * 8;
    float4 acc[8];
#pragma unroll
    for (int r = 0; r < 8; r++) acc[r] = make_float4(0.f, 0.f, 0.f, 0.f);

#pragma unroll 4
    for (int k = 0; k < DIM; k++) {
        float4 wv = *(const float4*)(W + (size_t)k * DIM + c0);
#pragma unroll
        for (int r = 0; r < 8; r++) {
            float a = hs[r0 + r][k];
            acc[r].x += a * wv.x;
            acc[r].y += a * wv.y;
            acc[r].z += a * wv.z;
            acc[r].w += a * wv.w;
        }
    }
#pragma unroll
    for (int r = 0; r < 8; r++) {
        int row = rowBase + r0 + r;
        if (row <= N_NODES) {   // includes sentinel row (hs zero-filled -> acc==0)
            uint2 pk;
            pk.x = rne_bf16(acc[r].x) | (rne_bf16(acc[r].y) << 16);
            pk.y = rne_bf16(acc[r].z) | (rne_bf16(acc[r].w) << 16);
            *(uint2*)(G + (size_t)row * DIM + c0) = pk;
        }
    }
}

__device__ __forceinline__ void accum8(float* acc, uint4 v) {
    acc[0] += bf16lo(v.x); acc[1] += bf16hi(v.x);
    acc[2] += bf16lo(v.y); acc[3] += bf16hi(v.y);
    acc[4] += bf16lo(v.z); acc[5] += bf16hi(v.z);
    acc[6] += bf16lo(v.w); acc[7] += bf16hi(v.w);
}

// Ungrouped full-row gather (structural floor ~109us: dur = max(12.8M line-req
// / 168K/us, FETCH / 3.3TB/s) -- model retro-predicts rounds 1/3/4/5). FROZEN.
__global__ __launch_bounds__(256) void agg_k(const unsigned short* __restrict__ G,
                                             const int* __restrict__ off,
                                             const int* __restrict__ nbArr,
                                             const int* __restrict__ csr,
                                             const float* __restrict__ bias,
                                             const float* __restrict__ epsp,
                                             float* __restrict__ out) {
    int tid = threadIdx.x;
    int lane = tid & 63;
    int node = blockIdx.x * 4 + (tid >> 6);
    int quarter = lane >> 4;   // 0..3: edge within the batch
    int q = lane & 15;         // 0..15: 16B slice (cols 8q..8q+7)
    float e1 = 1.0f + epsp[0];

    int offA = off[node];
    int nb = nbArr[node];
    const int* clb = csr + offA + quarter;

    float acc[8] = {0.f, 0.f, 0.f, 0.f, 0.f, 0.f, 0.f, 0.f};

    int b = 0;
    for (; b + 4 <= nb; b += 4) {
        int i0 = clb[0];
        int i1 = clb[4];
        int i2 = clb[8];
        int i3 = clb[12];
        clb += 16;
        uint4 g0 = *(const uint4*)(G + (size_t)i0 * DIM + q * 8);
        uint4 g1 = *(const uint4*)(G + (size_t)i1 * DIM + q * 8);
        uint4 g2 = *(const uint4*)(G + (size_t)i2 * DIM + q * 8);
        uint4 g3 = *(const uint4*)(G + (size_t)i3 * DIM + q * 8);
        accum8(acc, g0);
        accum8(acc, g1);
        accum8(acc, g2);
        accum8(acc, g3);
    }
    for (; b < nb; b++) {
        int i0 = clb[0];
        clb += 4;
        uint4 g0 = *(const uint4*)(G + (size_t)i0 * DIM + q * 8);
        accum8(acc, g0);
    }

    // reduce the 4 edge-copies of each column slice (lane bits 4,5)
#pragma unroll
    for (int j = 0; j < 8; j++) {
        acc[j] += __shfl_xor(acc[j], 16);
        acc[j] += __shfl_xor(acc[j], 32);
    }

    if (quarter == 0) {   // 16 lanes write the node's 128 cols (8 each)
        uint4 sv = *(const uint4*)(G + (size_t)node * DIM + q * 8);
        float4 b0 = *(const float4*)(bias + q * 8);
        float4 b1 = *(const float4*)(bias + q * 8 + 4);
        float* op = out + (size_t)node * DIM + q * 8;
        float4 r0, r1;
        r0.x = acc[0] + e1 * bf16lo(sv.x) + b0.x;
        r0.y = acc[1] + e1 * bf16hi(sv.x) + b0.y;
        r0.z = acc[2] + e1 * bf16lo(sv.y) + b0.z;
        r0.w = acc[3] + e1 * bf16hi(sv.y) + b0.w;
        r1.x = acc[4] + e1 * bf16lo(sv.z) + b1.x;
        r1.y = acc[5] + e1 * bf16hi(sv.z) + b1.y;
        r1.z = acc[6] + e1 * bf16lo(sv.w) + b1.z;
        r1.w = acc[7] + e1 * bf16hi(sv.w) + b1.w;
        *(float4*)op = r0;
        *(float4*)(op + 4) = r1;
    }
}

// ---------------- launch ----------------

extern "C" void kernel_launch(void* const* d_in, const int* in_sizes, int n_in,
                              void* d_out, int out_size, void* d_ws, size_t ws_size,
                              hipStream_t stream) {
    const float* feats = (const float*)d_in[0];
    const int* esrc = (const int*)d_in[1];
    const int* edst = (const int*)d_in[2];
    const float* Wm[3] = {(const float*)d_in[3], (const float*)d_in[6], (const float*)d_in[9]};
    const float* Bv[3] = {(const float*)d_in[4], (const float*)d_in[7], (const float*)d_in[10]};
    const float* Ev[3] = {(const float*)d_in[5], (const float*)d_in[8], (const float*)d_in[11]};
    float* out = (float*)d_out;

    char* ws = (char*)d_ws;
    unsigned short* bufG = (unsigned short*)(ws);        // 25,600,256 B : [100001][128] bf16
    int* ebuf       = (int*)(ws + 25600512);             // 12,800,000 B packed (src<<8|dst&255)
    int* csr        = (int*)(ws + 38400512);             // 16,003,072 B padded csr
    int* offsets    = (int*)(ws + 54411776);             //    400,000 B
    int* nbArr      = (int*)(ws + 54811776);             //    400,000 B
    int* bucketTotal= (int*)(ws + 55211776);             //      1,568 B
    int* bucketBase = (int*)(ws + 55213376);             //      1,572 B
    int* bucketCur  = (int*)(ws + 55215040);             //      1,568 B
    int* bhArr      = (int*)(ws + 55216640);             //  1,226,176 B per-block bucket hists

    // CSR build: bucket counting sort (stores de-scattered via LDS reordering)
    hipMemsetAsync(bucketTotal, 0, NBP * sizeof(int), stream);
    bhist_k<<<EB_BLOCKS, 256, 0, stream>>>(edst, bucketTotal, bhArr);
    bscan_k<<<1, 512, 0, stream>>>(bucketTotal, bucketBase, bucketCur);
    bscatter_k<<<EB_BLOCKS, 512, 0, stream>>>(esrc, edst, bhArr, bucketCur, ebuf);
    bfinal_k<<<NBUCK, 256, 0, stream>>>(ebuf, bucketBase, offsets, nbArr, csr);

    // 3 GIN layers: g = h @ W  (bufG, bf16);  h' = (1+eps)g + agg(g) + b  (d_out, f32)
    const float* h = feats;
    for (int l = 0; l < 3; l++) {
        gemm_k<<<(N_NODES + 64) / 64, 256, 0, stream>>>(h, Wm[l], bufG);  // covers sentinel row
        agg_k<<<N_NODES / 4, 256, 0, stream>>>(bufG, offsets, nbArr, csr, Bv[l], Ev[l], out);
        h = out;
    }
}

// Round 8
// 595.647 us; speedup vs baseline: 1.4005x; 1.1312x over previous
//
#include <hip/hip_runtime.h>

#define N_NODES 100000
#define N_EDGES 3200000
#define DIM 128
#define GROWS (N_NODES + 1)   // +1: sentinel all-zero row for csr padding
#define NBUCK 391        // ceil(100000/256) buckets of 256 nodes (dst>>8)
#define NBP 392          // padded
#define EB_BLOCKS 782    // ceil(3.2M / 4096) edge blocks (4096 edges/block)
#define BSLACK 2048      // per-bucket csr padding slack (>= 256 nodes * 3)
#define MAXPAD 9984      // LDS cap for one bucket's PADDED csr segment (mean ~8.6K, +15 sigma)

typedef __attribute__((ext_vector_type(8))) short short8;
typedef __attribute__((ext_vector_type(4))) float f32x4;

// ---------------- helpers ----------------

__device__ __forceinline__ unsigned rne_bf16(float f) {
    unsigned u = __builtin_bit_cast(unsigned, f);
    return (u + 0x7FFFu + ((u >> 16) & 1u)) >> 16;
}
__device__ __forceinline__ float bf16lo(unsigned u) {
    return __builtin_bit_cast(float, u << 16);
}
__device__ __forceinline__ float bf16hi(unsigned u) {
    return __builtin_bit_cast(float, u & 0xFFFF0000u);
}
// split x into bf16 hi + bf16 lo (lo captures the next 8 mantissa bits)
__device__ __forceinline__ void split2(float x, unsigned short& h, unsigned short& l) {
    unsigned hu = rne_bf16(x);
    h = (unsigned short)hu;
    l = (unsigned short)rne_bf16(x - bf16lo(hu));
}

// ---------------- CSR build: bucket counting sort (unchanged from round 7) ----------------

__global__ __launch_bounds__(256) void bhist_k(const int* __restrict__ dst,
                                               int* __restrict__ bucketTotal,
                                               int* __restrict__ bhArr) {
    __shared__ int h[NBP];
    int tid = threadIdx.x;
    for (int i = tid; i < NBP; i += 256) h[i] = 0;
    __syncthreads();
#pragma unroll
    for (int c = 0; c < 4; c++) {
        int e = blockIdx.x * 4096 + c * 1024 + tid * 4;
        if (e < N_EDGES) {
            int4 d4 = ((const int4*)dst)[e >> 2];
            atomicAdd(&h[d4.x >> 8], 1);
            atomicAdd(&h[d4.y >> 8], 1);
            atomicAdd(&h[d4.z >> 8], 1);
            atomicAdd(&h[d4.w >> 8], 1);
        }
    }
    __syncthreads();
    for (int i = tid; i < NBP; i += 256) {
        int v = h[i];
        bhArr[blockIdx.x * NBP + i] = v;
        if (v > 0) atomicAdd(&bucketTotal[i], v);
    }
}

__global__ __launch_bounds__(512) void bscan_k(const int* __restrict__ bucketTotal,
                                               int* __restrict__ bucketBase,
                                               int* __restrict__ bucketCursor) {
    __shared__ int tmp[512];
    int tid = threadIdx.x;
    int v = (tid < NBP) ? bucketTotal[tid] : 0;
    tmp[tid] = v;
    __syncthreads();
    for (int off = 1; off < 512; off <<= 1) {
        int x = tmp[tid];
        if (tid >= off) x += tmp[tid - off];
        __syncthreads();
        tmp[tid] = x;
        __syncthreads();
    }
    if (tid < NBP) {
        int excl = tmp[tid] - v;
        bucketBase[tid] = excl;
        bucketCursor[tid] = excl;
        if (tid == NBP - 1) bucketBase[NBP] = tmp[tid];
    }
}

__global__ __launch_bounds__(512) void bscatter_k(const int* __restrict__ src,
                                                  const int* __restrict__ dst,
                                                  const int* __restrict__ bhArr,
                                                  int* __restrict__ bucketCursor,
                                                  int* __restrict__ ebuf) {
    __shared__ int lcur0[NBP];
    __shared__ int pexc[NBP];
    __shared__ int lofs[NBP];
    __shared__ int pfx[512];
    __shared__ int sortedv[4096];
    __shared__ int gaddr[4096];
    int tid = threadIdx.x;
    int bid = blockIdx.x;
    int v = 0;
    if (tid < NBP) {
        v = bhArr[bid * NBP + tid];
        lcur0[tid] = (v > 0) ? atomicAdd(&bucketCursor[tid], v) : 0;
    }
    pfx[tid] = v;
    __syncthreads();
    for (int off = 1; off < 512; off <<= 1) {
        int x = pfx[tid];
        if (tid >= off) x += pfx[tid - off];
        __syncthreads();
        pfx[tid] = x;
        __syncthreads();
    }
    if (tid < NBP) {
        int ex = pfx[tid] - v;
        pexc[tid] = ex;
        lofs[tid] = ex;
    }
    __syncthreads();
#pragma unroll
    for (int c = 0; c < 2; c++) {
        int e = bid * 4096 + c * 2048 + tid * 4;
        if (e < N_EDGES) {
            int4 d4 = ((const int4*)dst)[e >> 2];
            int4 s4 = ((const int4*)src)[e >> 2];
            int b0 = d4.x >> 8, b1 = d4.y >> 8, b2 = d4.z >> 8, b3 = d4.w >> 8;
            int t0 = atomicAdd(&lofs[b0], 1);
            int t1 = atomicAdd(&lofs[b1], 1);
            int t2 = atomicAdd(&lofs[b2], 1);
            int t3 = atomicAdd(&lofs[b3], 1);
            sortedv[t0] = (s4.x << 8) | (d4.x & 255);
            sortedv[t1] = (s4.y << 8) | (d4.y & 255);
            sortedv[t2] = (s4.z << 8) | (d4.z & 255);
            sortedv[t3] = (s4.w << 8) | (d4.w & 255);
            gaddr[t0] = lcur0[b0] + (t0 - pexc[b0]);
            gaddr[t1] = lcur0[b1] + (t1 - pexc[b1]);
            gaddr[t2] = lcur0[b2] + (t2 - pexc[b2]);
            gaddr[t3] = lcur0[b3] + (t3 - pexc[b3]);
        }
    }
    __syncthreads();
    int totalE = min(4096, N_EDGES - bid * 4096);
    for (int j = tid; j < totalE; j += 512)
        ebuf[gaddr[j]] = sortedv[j];
}

__global__ __launch_bounds__(256) void bfinal_k(const int* __restrict__ ebuf,
                                                const int* __restrict__ bucketBase,
                                                int* __restrict__ offsets,
                                                int* __restrict__ nbArr,
                                                int* __restrict__ csr) {
    __shared__ int srt[MAXPAD];
    __shared__ int cnt[256];
    __shared__ int sc[256];
    __shared__ int cur[256];
    int tid = threadIdx.x;
    int b = blockIdx.x;
    int s = bucketBase[b], e = bucketBase[b + 1];
    int m = e - s;
    cnt[tid] = 0;
    __syncthreads();
    for (int i = tid; i < m; i += 256)
        atomicAdd(&cnt[ebuf[s + i] & 255], 1);
    __syncthreads();
    int c = cnt[tid];
    int pad = (c + 3) & ~3;
    sc[tid] = pad;
    __syncthreads();
    for (int off = 1; off < 256; off <<= 1) {
        int x = sc[tid];
        if (tid >= off) x += sc[tid - off];
        __syncthreads();
        sc[tid] = x;
        __syncthreads();
    }
    int pexcl = sc[tid] - pad;
    int gbase = s + b * BSLACK;
    int node = b * 256 + tid;
    if (node < N_NODES) {
        offsets[node] = gbase + pexcl;
        nbArr[node] = pad >> 2;
    }
    cur[tid] = pexcl;
    __syncthreads();
    int padTot = sc[255];
    if (padTot <= MAXPAD) {
        for (int j = tid; j < padTot; j += 256) srt[j] = N_NODES;
        __syncthreads();
        for (int i = tid; i < m; i += 256) {
            int pk = ebuf[s + i];
            int pos = atomicAdd(&cur[pk & 255], 1);
            srt[pos] = (int)((unsigned)pk >> 8);
        }
        __syncthreads();
        for (int j = tid; j < padTot; j += 256)
            csr[gbase + j] = srt[j];
    } else {
        for (int i = tid; i < m; i += 256) {
            int pk = ebuf[s + i];
            int pos = atomicAdd(&cur[pk & 255], 1);
            csr[gbase + pos] = (int)((unsigned)pk >> 8);
        }
        __syncthreads();
        int pend = pexcl + pad;
        for (int p2 = cur[tid]; p2 < pend; p2++) csr[gbase + p2] = N_NODES;
    }
}

// ---------------- per-layer compute ----------------

// prepw: W (f32 [128][128]) -> split-bf16 fragment-linear layouts Wh/Wl.
// Tile t = cb*4 + ks (cb: 16-col block, ks: 32-k step). Lane l supplies the
// B-fragment for mfma_f32_16x16x32_bf16: col = cb*16 + (l&15),
// k = ks*32 + (l>>4)*8 + j  (j=0..7, consecutive ushorts).
__global__ __launch_bounds__(64) void prepw_k(const float* __restrict__ W,
                                              unsigned short* __restrict__ Wh,
                                              unsigned short* __restrict__ Wl) {
    int l = threadIdx.x;
    int t = blockIdx.x;            // 0..31
    int col = ((t >> 2) << 4) + (l & 15);
    int k0 = ((t & 3) << 5) + ((l >> 4) << 3);
    unsigned hw[4], lw[4];
#pragma unroll
    for (int p = 0; p < 4; p++) {
        float x0 = W[(size_t)(k0 + 2 * p) * DIM + col];
        float x1 = W[(size_t)(k0 + 2 * p + 1) * DIM + col];
        unsigned short h0, l0, h1, l1;
        split2(x0, h0, l0);
        split2(x1, h1, l1);
        hw[p] = (unsigned)h0 | ((unsigned)h1 << 16);
        lw[p] = (unsigned)l0 | ((unsigned)l1 << 16);
    }
    size_t base = ((size_t)t * 64 + l) * 8;
    *(uint4*)(Wh + base) = make_uint4(hw[0], hw[1], hw[2], hw[3]);
    *(uint4*)(Wl + base) = make_uint4(lw[0], lw[1], lw[2], lw[3]);
}

// MFMA gemm, split-bf16 for f32-level precision:
//   G = bf16( Hh@Wh + Hl@Wh + Hh@Wl )   (lo*lo term ~2^-18, dropped)
// Wave = 16 rows; block = 4 waves = 64 rows; 8 col-blocks of 16.
// A-frag: row = lane&15 (H row), k = (lane>>4)*8+j  -> per-lane 2 float4 loads,
// split on the fly. B-frag: coalesced uint4 from prepw's fragment-linear Wh/Wl
// (L1/L2-resident, 64KB). C/D: col = lane&15, row = (lane>>4)*4+reg [m89].
// Memory-bound: 51.2MB H read + 25.6MB G write ~= 15-25us/layer.
__global__ __launch_bounds__(256) void gemm_k(const float* __restrict__ H,
                                              const unsigned short* __restrict__ Wh,
                                              const unsigned short* __restrict__ Wl,
                                              unsigned short* __restrict__ G) {
    int tid = threadIdx.x;
    int l = tid & 63;
    int wv = tid >> 6;
    int rowBase = blockIdx.x * 64 + wv * 16;
    int r = rowBase + (l & 15);
    int kg = (l >> 4) << 3;
    const float* hp = H + (size_t)((r < N_NODES) ? r : 0) * DIM;
    float zmask = (r < N_NODES) ? 1.0f : 0.0f;

    f32x4 acc[8];
#pragma unroll
    for (int cb = 0; cb < 8; cb++) acc[cb] = (f32x4){0.f, 0.f, 0.f, 0.f};

#pragma unroll
    for (int ks = 0; ks < 4; ks++) {
        float4 u0 = *(const float4*)(hp + ks * 32 + kg);
        float4 u1 = *(const float4*)(hp + ks * 32 + kg + 4);
        short8 ah, al;
        unsigned short hh, ll;
        split2(u0.x * zmask, hh, ll); ah[0] = hh; al[0] = ll;
        split2(u0.y * zmask, hh, ll); ah[1] = hh; al[1] = ll;
        split2(u0.z * zmask, hh, ll); ah[2] = hh; al[2] = ll;
        split2(u0.w * zmask, hh, ll); ah[3] = hh; al[3] = ll;
        split2(u1.x * zmask, hh, ll); ah[4] = hh; al[4] = ll;
        split2(u1.y * zmask, hh, ll); ah[5] = hh; al[5] = ll;
        split2(u1.z * zmask, hh, ll); ah[6] = hh; al[6] = ll;
        split2(u1.w * zmask, hh, ll); ah[7] = hh; al[7] = ll;
#pragma unroll
        for (int cb = 0; cb < 8; cb++) {
            size_t fidx = (size_t)((cb * 4 + ks) * 64 + l) * 8;
            short8 bh = *(const short8*)(Wh + fidx);
            short8 bl = *(const short8*)(Wl + fidx);
            acc[cb] = __builtin_amdgcn_mfma_f32_16x16x32_bf16(ah, bh, acc[cb], 0, 0, 0);
            acc[cb] = __builtin_amdgcn_mfma_f32_16x16x32_bf16(al, bh, acc[cb], 0, 0, 0);
            acc[cb] = __builtin_amdgcn_mfma_f32_16x16x32_bf16(ah, bl, acc[cb], 0, 0, 0);
        }
    }

    int ro = rowBase + ((l >> 4) << 2);
    int co = l & 15;
#pragma unroll
    for (int cb = 0; cb < 8; cb++) {
#pragma unroll
        for (int j = 0; j < 4; j++) {
            int rr = ro + j;
            if (rr <= N_NODES)   // row N_NODES: sentinel, acc==0 there (zmask)
                G[(size_t)rr * DIM + cb * 16 + co] = (unsigned short)rne_bf16(acc[cb][j]);
        }
    }
}

__device__ __forceinline__ void accum8(float* acc, uint4 v) {
    acc[0] += bf16lo(v.x); acc[1] += bf16hi(v.x);
    acc[2] += bf16lo(v.y); acc[3] += bf16hi(v.y);
    acc[4] += bf16lo(v.z); acc[5] += bf16hi(v.z);
    acc[6] += bf16lo(v.w); acc[7] += bf16hi(v.w);
}

// Ungrouped full-row gather (structural floor ~108us). FROZEN since round 5.
__global__ __launch_bounds__(256) void agg_k(const unsigned short* __restrict__ G,
                                             const int* __restrict__ off,
                                             const int* __restrict__ nbArr,
                                             const int* __restrict__ csr,
                                             const float* __restrict__ bias,
                                             const float* __restrict__ epsp,
                                             float* __restrict__ out) {
    int tid = threadIdx.x;
    int lane = tid & 63;
    int node = blockIdx.x * 4 + (tid >> 6);
    int quarter = lane >> 4;
    int q = lane & 15;
    float e1 = 1.0f + epsp[0];

    int offA = off[node];
    int nb = nbArr[node];
    const int* clb = csr + offA + quarter;

    float acc[8] = {0.f, 0.f, 0.f, 0.f, 0.f, 0.f, 0.f, 0.f};

    int b = 0;
    for (; b + 4 <= nb; b += 4) {
        int i0 = clb[0];
        int i1 = clb[4];
        int i2 = clb[8];
        int i3 = clb[12];
        clb += 16;
        uint4 g0 = *(const uint4*)(G + (size_t)i0 * DIM + q * 8);
        uint4 g1 = *(const uint4*)(G + (size_t)i1 * DIM + q * 8);
        uint4 g2 = *(const uint4*)(G + (size_t)i2 * DIM + q * 8);
        uint4 g3 = *(const uint4*)(G + (size_t)i3 * DIM + q * 8);
        accum8(acc, g0);
        accum8(acc, g1);
        accum8(acc, g2);
        accum8(acc, g3);
    }
    for (; b < nb; b++) {
        int i0 = clb[0];
        clb += 4;
        uint4 g0 = *(const uint4*)(G + (size_t)i0 * DIM + q * 8);
        accum8(acc, g0);
    }

#pragma unroll
    for (int j = 0; j < 8; j++) {
        acc[j] += __shfl_xor(acc[j], 16);
        acc[j] += __shfl_xor(acc[j], 32);
    }

    if (quarter == 0) {
        uint4 sv = *(const uint4*)(G + (size_t)node * DIM + q * 8);
        float4 b0 = *(const float4*)(bias + q * 8);
        float4 b1 = *(const float4*)(bias + q * 8 + 4);
        float* op = out + (size_t)node * DIM + q * 8;
        float4 r0, r1;
        r0.x = acc[0] + e1 * bf16lo(sv.x) + b0.x;
        r0.y = acc[1] + e1 * bf16hi(sv.x) + b0.y;
        r0.z = acc[2] + e1 * bf16lo(sv.y) + b0.z;
        r0.w = acc[3] + e1 * bf16hi(sv.y) + b0.w;
        r1.x = acc[4] + e1 * bf16lo(sv.z) + b1.x;
        r1.y = acc[5] + e1 * bf16hi(sv.z) + b1.y;
        r1.z = acc[6] + e1 * bf16lo(sv.w) + b1.z;
        r1.w = acc[7] + e1 * bf16hi(sv.w) + b1.w;
        *(float4*)op = r0;
        *(float4*)(op + 4) = r1;
    }
}

// ---------------- launch ----------------

extern "C" void kernel_launch(void* const* d_in, const int* in_sizes, int n_in,
                              void* d_out, int out_size, void* d_ws, size_t ws_size,
                              hipStream_t stream) {
    const float* feats = (const float*)d_in[0];
    const int* esrc = (const int*)d_in[1];
    const int* edst = (const int*)d_in[2];
    const float* Wm[3] = {(const float*)d_in[3], (const float*)d_in[6], (const float*)d_in[9]};
    const float* Bv[3] = {(const float*)d_in[4], (const float*)d_in[7], (const float*)d_in[10]};
    const float* Ev[3] = {(const float*)d_in[5], (const float*)d_in[8], (const float*)d_in[11]};
    float* out = (float*)d_out;

    char* ws = (char*)d_ws;
    unsigned short* bufG = (unsigned short*)(ws);        // 25,600,256 B : [100001][128] bf16
    int* ebuf       = (int*)(ws + 25600512);             // 12,800,000 B packed (src<<8|dst&255)
    int* csr        = (int*)(ws + 38400512);             // 16,003,072 B padded csr
    int* offsets    = (int*)(ws + 54411776);             //    400,000 B
    int* nbArr      = (int*)(ws + 54811776);             //    400,000 B
    int* bucketTotal= (int*)(ws + 55211776);             //      1,568 B
    int* bucketBase = (int*)(ws + 55213376);             //      1,572 B
    int* bucketCur  = (int*)(ws + 55215040);             //      1,568 B
    int* bhArr      = (int*)(ws + 55216640);             //  1,226,176 B per-block bucket hists
    unsigned short* wfrag = (unsigned short*)(ws + 56442816);  // 6 x 32,768 B: Wh0,Wl0,Wh1,Wl1,Wh2,Wl2

    // W fragment prep (split-bf16, fragment-linear) -- once per layer, ~2us each
    for (int l = 0; l < 3; l++)
        prepw_k<<<32, 64, 0, stream>>>(Wm[l], wfrag + l * 32768, wfrag + l * 32768 + 16384);

    // CSR build: bucket counting sort (stores de-scattered via LDS reordering)
    hipMemsetAsync(bucketTotal, 0, NBP * sizeof(int), stream);
    bhist_k<<<EB_BLOCKS, 256, 0, stream>>>(edst, bucketTotal, bhArr);
    bscan_k<<<1, 512, 0, stream>>>(bucketTotal, bucketBase, bucketCur);
    bscatter_k<<<EB_BLOCKS, 512, 0, stream>>>(esrc, edst, bhArr, bucketCur, ebuf);
    bfinal_k<<<NBUCK, 256, 0, stream>>>(ebuf, bucketBase, offsets, nbArr, csr);

    // 3 GIN layers: g = h @ W  (MFMA split-bf16 -> bufG);  h' = (1+eps)g + agg(g) + b
    const float* h = feats;
    for (int l = 0; l < 3; l++) {
        gemm_k<<<(N_NODES + 63) / 64, 256, 0, stream>>>(h, wfrag + l * 32768,
                                                        wfrag + l * 32768 + 16384, bufG);
        agg_k<<<N_NODES / 4, 256, 0, stream>>>(bufG, offsets, nbArr, csr, Bv[l], Ev[l], out);
        h = out;
    }
}

// Round 9
// 563.755 us; speedup vs baseline: 1.4797x; 1.0566x over previous
//
#include <hip/hip_runtime.h>

#define N_NODES 100000
#define N_EDGES 3200000
#define DIM 128
#define GROWS (N_NODES + 1)   // +1: sentinel all-zero row for csr padding
#define NBUCK 391        // ceil(100000/256) buckets of 256 nodes (dst>>8)
#define NBP 392          // padded
#define EB_BLOCKS 782    // ceil(3.2M / 4096) edge blocks (4096 edges/block)
#define BSLACK 2048      // per-bucket csr padding slack (>= 256 nodes * 3)
#define MAXPAD 9984      // LDS cap for one bucket's PADDED csr segment (mean ~8.6K, +15 sigma)

typedef __attribute__((ext_vector_type(8))) short short8;
typedef __attribute__((ext_vector_type(4))) float f32x4;

// ---------------- helpers ----------------

__device__ __forceinline__ unsigned rne_bf16(float f) {
    unsigned u = __builtin_bit_cast(unsigned, f);
    return (u + 0x7FFFu + ((u >> 16) & 1u)) >> 16;
}
__device__ __forceinline__ float bf16lo(unsigned u) {
    return __builtin_bit_cast(float, u << 16);
}
__device__ __forceinline__ float bf16hi(unsigned u) {
    return __builtin_bit_cast(float, u & 0xFFFF0000u);
}
// split x into bf16 hi + bf16 lo (lo captures the next 8 mantissa bits)
__device__ __forceinline__ void split2(float x, unsigned short& h, unsigned short& l) {
    unsigned hu = rne_bf16(x);
    h = (unsigned short)hu;
    l = (unsigned short)rne_bf16(x - bf16lo(hu));
}

// ---------------- CSR build: bucket counting sort (unchanged from round 7) ----------------

__global__ __launch_bounds__(256) void bhist_k(const int* __restrict__ dst,
                                               int* __restrict__ bucketTotal,
                                               int* __restrict__ bhArr) {
    __shared__ int h[NBP];
    int tid = threadIdx.x;
    for (int i = tid; i < NBP; i += 256) h[i] = 0;
    __syncthreads();
#pragma unroll
    for (int c = 0; c < 4; c++) {
        int e = blockIdx.x * 4096 + c * 1024 + tid * 4;
        if (e < N_EDGES) {
            int4 d4 = ((const int4*)dst)[e >> 2];
            atomicAdd(&h[d4.x >> 8], 1);
            atomicAdd(&h[d4.y >> 8], 1);
            atomicAdd(&h[d4.z >> 8], 1);
            atomicAdd(&h[d4.w >> 8], 1);
        }
    }
    __syncthreads();
    for (int i = tid; i < NBP; i += 256) {
        int v = h[i];
        bhArr[blockIdx.x * NBP + i] = v;
        if (v > 0) atomicAdd(&bucketTotal[i], v);
    }
}

__global__ __launch_bounds__(512) void bscan_k(const int* __restrict__ bucketTotal,
                                               int* __restrict__ bucketBase,
                                               int* __restrict__ bucketCursor) {
    __shared__ int tmp[512];
    int tid = threadIdx.x;
    int v = (tid < NBP) ? bucketTotal[tid] : 0;
    tmp[tid] = v;
    __syncthreads();
    for (int off = 1; off < 512; off <<= 1) {
        int x = tmp[tid];
        if (tid >= off) x += tmp[tid - off];
        __syncthreads();
        tmp[tid] = x;
        __syncthreads();
    }
    if (tid < NBP) {
        int excl = tmp[tid] - v;
        bucketBase[tid] = excl;
        bucketCursor[tid] = excl;
        if (tid == NBP - 1) bucketBase[NBP] = tmp[tid];
    }
}

__global__ __launch_bounds__(512) void bscatter_k(const int* __restrict__ src,
                                                  const int* __restrict__ dst,
                                                  const int* __restrict__ bhArr,
                                                  int* __restrict__ bucketCursor,
                                                  int* __restrict__ ebuf) {
    __shared__ int lcur0[NBP];
    __shared__ int pexc[NBP];
    __shared__ int lofs[NBP];
    __shared__ int pfx[512];
    __shared__ int sortedv[4096];
    __shared__ int gaddr[4096];
    int tid = threadIdx.x;
    int bid = blockIdx.x;
    int v = 0;
    if (tid < NBP) {
        v = bhArr[bid * NBP + tid];
        lcur0[tid] = (v > 0) ? atomicAdd(&bucketCursor[tid], v) : 0;
    }
    pfx[tid] = v;
    __syncthreads();
    for (int off = 1; off < 512; off <<= 1) {
        int x = pfx[tid];
        if (tid >= off) x += pfx[tid - off];
        __syncthreads();
        pfx[tid] = x;
        __syncthreads();
    }
    if (tid < NBP) {
        int ex = pfx[tid] - v;
        pexc[tid] = ex;
        lofs[tid] = ex;
    }
    __syncthreads();
#pragma unroll
    for (int c = 0; c < 2; c++) {
        int e = bid * 4096 + c * 2048 + tid * 4;
        if (e < N_EDGES) {
            int4 d4 = ((const int4*)dst)[e >> 2];
            int4 s4 = ((const int4*)src)[e >> 2];
            int b0 = d4.x >> 8, b1 = d4.y >> 8, b2 = d4.z >> 8, b3 = d4.w >> 8;
            int t0 = atomicAdd(&lofs[b0], 1);
            int t1 = atomicAdd(&lofs[b1], 1);
            int t2 = atomicAdd(&lofs[b2], 1);
            int t3 = atomicAdd(&lofs[b3], 1);
            sortedv[t0] = (s4.x << 8) | (d4.x & 255);
            sortedv[t1] = (s4.y << 8) | (d4.y & 255);
            sortedv[t2] = (s4.z << 8) | (d4.z & 255);
            sortedv[t3] = (s4.w << 8) | (d4.w & 255);
            gaddr[t0] = lcur0[b0] + (t0 - pexc[b0]);
            gaddr[t1] = lcur0[b1] + (t1 - pexc[b1]);
            gaddr[t2] = lcur0[b2] + (t2 - pexc[b2]);
            gaddr[t3] = lcur0[b3] + (t3 - pexc[b3]);
        }
    }
    __syncthreads();
    int totalE = min(4096, N_EDGES - bid * 4096);
    for (int j = tid; j < totalE; j += 512)
        ebuf[gaddr[j]] = sortedv[j];
}

__global__ __launch_bounds__(256) void bfinal_k(const int* __restrict__ ebuf,
                                                const int* __restrict__ bucketBase,
                                                int* __restrict__ offsets,
                                                int* __restrict__ nbArr,
                                                int* __restrict__ csr) {
    __shared__ int srt[MAXPAD];
    __shared__ int cnt[256];
    __shared__ int sc[256];
    __shared__ int cur[256];
    int tid = threadIdx.x;
    int b = blockIdx.x;
    int s = bucketBase[b], e = bucketBase[b + 1];
    int m = e - s;
    cnt[tid] = 0;
    __syncthreads();
    for (int i = tid; i < m; i += 256)
        atomicAdd(&cnt[ebuf[s + i] & 255], 1);
    __syncthreads();
    int c = cnt[tid];
    int pad = (c + 3) & ~3;
    sc[tid] = pad;
    __syncthreads();
    for (int off = 1; off < 256; off <<= 1) {
        int x = sc[tid];
        if (tid >= off) x += sc[tid - off];
        __syncthreads();
        sc[tid] = x;
        __syncthreads();
    }
    int pexcl = sc[tid] - pad;
    int gbase = s + b * BSLACK;
    int node = b * 256 + tid;
    if (node < N_NODES) {
        offsets[node] = gbase + pexcl;
        nbArr[node] = pad >> 2;
    }
    cur[tid] = pexcl;
    __syncthreads();
    int padTot = sc[255];
    if (padTot <= MAXPAD) {
        for (int j = tid; j < padTot; j += 256) srt[j] = N_NODES;
        __syncthreads();
        for (int i = tid; i < m; i += 256) {
            int pk = ebuf[s + i];
            int pos = atomicAdd(&cur[pk & 255], 1);
            srt[pos] = (int)((unsigned)pk >> 8);
        }
        __syncthreads();
        for (int j = tid; j < padTot; j += 256)
            csr[gbase + j] = srt[j];
    } else {
        for (int i = tid; i < m; i += 256) {
            int pk = ebuf[s + i];
            int pos = atomicAdd(&cur[pk & 255], 1);
            csr[gbase + pos] = (int)((unsigned)pk >> 8);
        }
        __syncthreads();
        int pend = pexcl + pad;
        for (int p2 = cur[tid]; p2 < pend; p2++) csr[gbase + p2] = N_NODES;
    }
}

// ---------------- per-layer compute ----------------

// prepw (all 3 layers in one launch): W (f32 [128][128]) -> split-bf16
// fragment-linear Wh/Wl. blockIdx = layer*32 + tile; tile t = cb*4 + ks.
// Lane l supplies B-frag: col = cb*16 + (l&15), k = ks*32 + (l>>4)*8 + j.
__global__ __launch_bounds__(64) void prepw_k(const float* __restrict__ W0,
                                              const float* __restrict__ W1,
                                              const float* __restrict__ W2,
                                              unsigned short* __restrict__ wfrag) {
    int l = threadIdx.x;
    int lay = blockIdx.x >> 5;
    int t = blockIdx.x & 31;
    const float* W = (lay == 0) ? W0 : (lay == 1) ? W1 : W2;
    unsigned short* Wh = wfrag + lay * 32768;
    unsigned short* Wl = Wh + 16384;
    int col = ((t >> 2) << 4) + (l & 15);
    int k0 = ((t & 3) << 5) + ((l >> 4) << 3);
    unsigned hw[4], lw[4];
#pragma unroll
    for (int p = 0; p < 4; p++) {
        float x0 = W[(size_t)(k0 + 2 * p) * DIM + col];
        float x1 = W[(size_t)(k0 + 2 * p + 1) * DIM + col];
        unsigned short h0, l0, h1, l1;
        split2(x0, h0, l0);
        split2(x1, h1, l1);
        hw[p] = (unsigned)h0 | ((unsigned)h1 << 16);
        lw[p] = (unsigned)l0 | ((unsigned)l1 << 16);
    }
    size_t base = ((size_t)t * 64 + l) * 8;
    *(uint4*)(Wh + base) = make_uint4(hw[0], hw[1], hw[2], hw[3]);
    *(uint4*)(Wl + base) = make_uint4(lw[0], lw[1], lw[2], lw[3]);
}

// MFMA gemm (layer 1 only), split-bf16: G = bf16(Hh@Wh + Hl@Wh + Hh@Wl).
__global__ __launch_bounds__(256) void gemm_k(const float* __restrict__ H,
                                              const unsigned short* __restrict__ Wh,
                                              const unsigned short* __restrict__ Wl,
                                              unsigned short* __restrict__ G) {
    int tid = threadIdx.x;
    int l = tid & 63;
    int wv = tid >> 6;
    int rowBase = blockIdx.x * 64 + wv * 16;
    int r = rowBase + (l & 15);
    int kg = (l >> 4) << 3;
    const float* hp = H + (size_t)((r < N_NODES) ? r : 0) * DIM;
    float zmask = (r < N_NODES) ? 1.0f : 0.0f;

    f32x4 acc[8];
#pragma unroll
    for (int cb = 0; cb < 8; cb++) acc[cb] = (f32x4){0.f, 0.f, 0.f, 0.f};

#pragma unroll
    for (int ks = 0; ks < 4; ks++) {
        float4 u0 = *(const float4*)(hp + ks * 32 + kg);
        float4 u1 = *(const float4*)(hp + ks * 32 + kg + 4);
        short8 ah, al;
        unsigned short hh, ll;
        split2(u0.x * zmask, hh, ll); ah[0] = hh; al[0] = ll;
        split2(u0.y * zmask, hh, ll); ah[1] = hh; al[1] = ll;
        split2(u0.z * zmask, hh, ll); ah[2] = hh; al[2] = ll;
        split2(u0.w * zmask, hh, ll); ah[3] = hh; al[3] = ll;
        split2(u1.x * zmask, hh, ll); ah[4] = hh; al[4] = ll;
        split2(u1.y * zmask, hh, ll); ah[5] = hh; al[5] = ll;
        split2(u1.z * zmask, hh, ll); ah[6] = hh; al[6] = ll;
        split2(u1.w * zmask, hh, ll); ah[7] = hh; al[7] = ll;
#pragma unroll
        for (int cb = 0; cb < 8; cb++) {
            size_t fidx = (size_t)((cb * 4 + ks) * 64 + l) * 8;
            short8 bh = *(const short8*)(Wh + fidx);
            short8 bl = *(const short8*)(Wl + fidx);
            acc[cb] = __builtin_amdgcn_mfma_f32_16x16x32_bf16(ah, bh, acc[cb], 0, 0, 0);
            acc[cb] = __builtin_amdgcn_mfma_f32_16x16x32_bf16(al, bh, acc[cb], 0, 0, 0);
            acc[cb] = __builtin_amdgcn_mfma_f32_16x16x32_bf16(ah, bl, acc[cb], 0, 0, 0);
        }
    }

    int ro = rowBase + ((l >> 4) << 2);
    int co = l & 15;
#pragma unroll
    for (int cb = 0; cb < 8; cb++) {
#pragma unroll
        for (int j = 0; j < 4; j++) {
            int rr = ro + j;
            if (rr <= N_NODES)
                G[(size_t)rr * DIM + cb * 16 + co] = (unsigned short)rne_bf16(acc[cb][j]);
        }
    }
}

__device__ __forceinline__ void accum8(float* acc, uint4 v) {
    acc[0] += bf16lo(v.x); acc[1] += bf16hi(v.x);
    acc[2] += bf16lo(v.y); acc[3] += bf16hi(v.y);
    acc[4] += bf16lo(v.z); acc[5] += bf16hi(v.z);
    acc[6] += bf16lo(v.w); acc[7] += bf16hi(v.w);
}

// FUSED agg_l + gemm_{l+1}: 1024 thr = 16 waves = 16 nodes. Gather loop is
// bit-identical to agg_k (1 node/wave). h' = (1+eps)g + agg + b goes to a
// padded [16][132] f32 LDS tile (no 51.2MB f32 HBM round-trip), then waves
// 0..7 run the split-bf16 MFMA (one 16-col block each, same accumulation
// order as gemm_k -> bit-identical G') and store G_{l+1} directly.
__global__ __launch_bounds__(1024) void aggemm_k(const unsigned short* __restrict__ G,
                                                 const int* __restrict__ off,
                                                 const int* __restrict__ nbArr,
                                                 const int* __restrict__ csr,
                                                 const float* __restrict__ bias,
                                                 const float* __restrict__ epsp,
                                                 const unsigned short* __restrict__ Wh,
                                                 const unsigned short* __restrict__ Wl,
                                                 unsigned short* __restrict__ Gout) {
    __shared__ float hsm[16][132];   // +4 pad: 2-way max bank aliasing on A-frag reads
    int tid = threadIdx.x;
    int lane = tid & 63;
    int wid = tid >> 6;              // 0..15 = node slot
    int node = blockIdx.x * 16 + wid;
    int quarter = lane >> 4;
    int q = lane & 15;
    float e1 = 1.0f + epsp[0];

    // ---- gather phase (identical math/order to agg_k) ----
    int offA = off[node];
    int nb = nbArr[node];
    const int* clb = csr + offA + quarter;
    float acc[8] = {0.f, 0.f, 0.f, 0.f, 0.f, 0.f, 0.f, 0.f};
    int b = 0;
    for (; b + 4 <= nb; b += 4) {
        int i0 = clb[0];
        int i1 = clb[4];
        int i2 = clb[8];
        int i3 = clb[12];
        clb += 16;
        uint4 g0 = *(const uint4*)(G + (size_t)i0 * DIM + q * 8);
        uint4 g1 = *(const uint4*)(G + (size_t)i1 * DIM + q * 8);
        uint4 g2 = *(const uint4*)(G + (size_t)i2 * DIM + q * 8);
        uint4 g3 = *(const uint4*)(G + (size_t)i3 * DIM + q * 8);
        accum8(acc, g0);
        accum8(acc, g1);
        accum8(acc, g2);
        accum8(acc, g3);
    }
    for (; b < nb; b++) {
        int i0 = clb[0];
        clb += 4;
        uint4 g0 = *(const uint4*)(G + (size_t)i0 * DIM + q * 8);
        accum8(acc, g0);
    }
#pragma unroll
    for (int j = 0; j < 8; j++) {
        acc[j] += __shfl_xor(acc[j], 16);
        acc[j] += __shfl_xor(acc[j], 32);
    }
    if (quarter == 0) {
        uint4 sv = *(const uint4*)(G + (size_t)node * DIM + q * 8);
        float4 b0 = *(const float4*)(bias + q * 8);
        float4 b1 = *(const float4*)(bias + q * 8 + 4);
        float4 r0, r1;
        r0.x = acc[0] + e1 * bf16lo(sv.x) + b0.x;
        r0.y = acc[1] + e1 * bf16hi(sv.x) + b0.y;
        r0.z = acc[2] + e1 * bf16lo(sv.y) + b0.z;
        r0.w = acc[3] + e1 * bf16hi(sv.y) + b0.w;
        r1.x = acc[4] + e1 * bf16lo(sv.z) + b1.x;
        r1.y = acc[5] + e1 * bf16hi(sv.z) + b1.y;
        r1.z = acc[6] + e1 * bf16lo(sv.w) + b1.z;
        r1.w = acc[7] + e1 * bf16hi(sv.w) + b1.w;
        *(float4*)&hsm[wid][q * 8] = r0;
        *(float4*)&hsm[wid][q * 8 + 4] = r1;
    }
    __syncthreads();

    // ---- MFMA phase: waves 0..7, one 16-col block each ----
    if (wid < 8) {
        int cb = wid;
        int rl = lane & 15;
        int kg = (lane >> 4) << 3;
        f32x4 o = (f32x4){0.f, 0.f, 0.f, 0.f};
#pragma unroll
        for (int ks = 0; ks < 4; ks++) {
            const float* ap = &hsm[rl][ks * 32 + kg];
            short8 ah, al;
            unsigned short hh, ll;
#pragma unroll
            for (int j = 0; j < 8; j++) {
                split2(ap[j], hh, ll);
                ah[j] = hh;
                al[j] = ll;
            }
            size_t fidx = (size_t)((cb * 4 + ks) * 64 + lane) * 8;
            short8 bh = *(const short8*)(Wh + fidx);
            short8 bl = *(const short8*)(Wl + fidx);
            o = __builtin_amdgcn_mfma_f32_16x16x32_bf16(ah, bh, o, 0, 0, 0);
            o = __builtin_amdgcn_mfma_f32_16x16x32_bf16(al, bh, o, 0, 0, 0);
            o = __builtin_amdgcn_mfma_f32_16x16x32_bf16(ah, bl, o, 0, 0, 0);
        }
        int ro = blockIdx.x * 16 + ((lane >> 4) << 2);
        int co = cb * 16 + rl;
#pragma unroll
        for (int j = 0; j < 4; j++)
            Gout[(size_t)(ro + j) * DIM + co] = (unsigned short)rne_bf16(o[j]);
    } else if (wid == 8 && blockIdx.x == 0) {
        // sentinel row of Gout = zeros (read by next layer's gather padding)
        ((unsigned*)(Gout + (size_t)N_NODES * DIM))[lane] = 0u;
    }
}

// Ungrouped full-row gather (structural floor ~108us). FROZEN. Final layer only.
__global__ __launch_bounds__(256) void agg_k(const unsigned short* __restrict__ G,
                                             const int* __restrict__ off,
                                             const int* __restrict__ nbArr,
                                             const int* __restrict__ csr,
                                             const float* __restrict__ bias,
                                             const float* __restrict__ epsp,
                                             float* __restrict__ out) {
    int tid = threadIdx.x;
    int lane = tid & 63;
    int node = blockIdx.x * 4 + (tid >> 6);
    int quarter = lane >> 4;
    int q = lane & 15;
    float e1 = 1.0f + epsp[0];

    int offA = off[node];
    int nb = nbArr[node];
    const int* clb = csr + offA + quarter;

    float acc[8] = {0.f, 0.f, 0.f, 0.f, 0.f, 0.f, 0.f, 0.f};

    int b = 0;
    for (; b + 4 <= nb; b += 4) {
        int i0 = clb[0];
        int i1 = clb[4];
        int i2 = clb[8];
        int i3 = clb[12];
        clb += 16;
        uint4 g0 = *(const uint4*)(G + (size_t)i0 * DIM + q * 8);
        uint4 g1 = *(const uint4*)(G + (size_t)i1 * DIM + q * 8);
        uint4 g2 = *(const uint4*)(G + (size_t)i2 * DIM + q * 8);
        uint4 g3 = *(const uint4*)(G + (size_t)i3 * DIM + q * 8);
        accum8(acc, g0);
        accum8(acc, g1);
        accum8(acc, g2);
        accum8(acc, g3);
    }
    for (; b < nb; b++) {
        int i0 = clb[0];
        clb += 4;
        uint4 g0 = *(const uint4*)(G + (size_t)i0 * DIM + q * 8);
        accum8(acc, g0);
    }

#pragma unroll
    for (int j = 0; j < 8; j++) {
        acc[j] += __shfl_xor(acc[j], 16);
        acc[j] += __shfl_xor(acc[j], 32);
    }

    if (quarter == 0) {
        uint4 sv = *(const uint4*)(G + (size_t)node * DIM + q * 8);
        float4 b0 = *(const float4*)(bias + q * 8);
        float4 b1 = *(const float4*)(bias + q * 8 + 4);
        float* op = out + (size_t)node * DIM + q * 8;
        float4 r0, r1;
        r0.x = acc[0] + e1 * bf16lo(sv.x) + b0.x;
        r0.y = acc[1] + e1 * bf16hi(sv.x) + b0.y;
        r0.z = acc[2] + e1 * bf16lo(sv.y) + b0.z;
        r0.w = acc[3] + e1 * bf16hi(sv.y) + b0.w;
        r1.x = acc[4] + e1 * bf16lo(sv.z) + b1.x;
        r1.y = acc[5] + e1 * bf16hi(sv.z) + b1.y;
        r1.z = acc[6] + e1 * bf16lo(sv.w) + b1.z;
        r1.w = acc[7] + e1 * bf16hi(sv.w) + b1.w;
        *(float4*)op = r0;
        *(float4*)(op + 4) = r1;
    }
}

// ---------------- launch ----------------

extern "C" void kernel_launch(void* const* d_in, const int* in_sizes, int n_in,
                              void* d_out, int out_size, void* d_ws, size_t ws_size,
                              hipStream_t stream) {
    const float* feats = (const float*)d_in[0];
    const int* esrc = (const int*)d_in[1];
    const int* edst = (const int*)d_in[2];
    const float* Wm[3] = {(const float*)d_in[3], (const float*)d_in[6], (const float*)d_in[9]};
    const float* Bv[3] = {(const float*)d_in[4], (const float*)d_in[7], (const float*)d_in[10]};
    const float* Ev[3] = {(const float*)d_in[5], (const float*)d_in[8], (const float*)d_in[11]};
    float* out = (float*)d_out;

    char* ws = (char*)d_ws;
    unsigned short* bufG = (unsigned short*)(ws);        // 25,600,256 B : [100001][128] bf16 (G_A)
    int* ebuf       = (int*)(ws + 25600512);             // 12,800,000 B packed (src<<8|dst&255)
    int* csr        = (int*)(ws + 38400512);             // 16,003,072 B padded csr
    int* offsets    = (int*)(ws + 54411776);             //    400,000 B
    int* nbArr      = (int*)(ws + 54811776);             //    400,000 B
    int* bucketTotal= (int*)(ws + 55211776);             //      1,568 B
    int* bucketBase = (int*)(ws + 55213376);             //      1,572 B
    int* bucketCur  = (int*)(ws + 55215040);             //      1,568 B
    int* bhArr      = (int*)(ws + 55216640);             //  1,226,176 B per-block bucket hists
    unsigned short* wfrag = (unsigned short*)(ws + 56442816);  // 6 x 32,768 B: Wh0,Wl0,Wh1,Wl1,Wh2,Wl2

    unsigned short* G_A = bufG;
    unsigned short* G_B = (unsigned short*)d_out;  // 25.6MB bf16 scratch inside the 51.2MB
                                                   // output buffer; dead before agg3 overwrites out

    // W fragment prep (split-bf16, fragment-linear), all 3 layers in one launch
    prepw_k<<<96, 64, 0, stream>>>(Wm[0], Wm[1], Wm[2], wfrag);

    // CSR build: bucket counting sort (stores de-scattered via LDS reordering)
    hipMemsetAsync(bucketTotal, 0, NBP * sizeof(int), stream);
    bhist_k<<<EB_BLOCKS, 256, 0, stream>>>(edst, bucketTotal, bhArr);
    bscan_k<<<1, 512, 0, stream>>>(bucketTotal, bucketBase, bucketCur);
    bscatter_k<<<EB_BLOCKS, 512, 0, stream>>>(esrc, edst, bhArr, bucketCur, ebuf);
    bfinal_k<<<NBUCK, 256, 0, stream>>>(ebuf, bucketBase, offsets, nbArr, csr);

    // layer 1 gemm: G_A = bf16(feats @ W0)
    gemm_k<<<(N_NODES + 64) / 64, 256, 0, stream>>>(feats, wfrag, wfrag + 16384, G_A);
    // fused agg1+gemm2: G_B = bf16(h1' @ W1)
    aggemm_k<<<N_NODES / 16, 1024, 0, stream>>>(G_A, offsets, nbArr, csr, Bv[0], Ev[0],
                                                wfrag + 32768, wfrag + 49152, G_B);
    // fused agg2+gemm3: G_A = bf16(h2' @ W2)
    aggemm_k<<<N_NODES / 16, 1024, 0, stream>>>(G_B, offsets, nbArr, csr, Bv[1], Ev[1],
                                                wfrag + 65536, wfrag + 81920, G_A);
    // final agg: out = (1+eps)g3 + agg(g3) + b3  (f32)
    agg_k<<<N_NODES / 4, 256, 0, stream>>>(G_A, offsets, nbArr, csr, Bv[2], Ev[2], out);
}

// Round 10
// 555.975 us; speedup vs baseline: 1.5004x; 1.0140x over previous
//
#include <hip/hip_runtime.h>

#define N_NODES 100000
#define N_EDGES 3200000
#define DIM 128
#define GROWS (N_NODES + 1)   // +1: sentinel all-zero row for csr padding
#define NBUCK 391        // ceil(100000/256) buckets of 256 nodes (dst>>8)
#define NBP 392          // padded
#define EB_BLOCKS 782    // ceil(3.2M / 4096) edge blocks (4096 edges/block)
#define BSLACK 2048      // per-bucket csr padding slack (>= 256 nodes * 3)
#define MAXPAD 9984      // LDS cap for one bucket's PADDED csr segment (mean ~8.6K, +15 sigma)

typedef __attribute__((ext_vector_type(8))) short short8;
typedef __attribute__((ext_vector_type(4))) float f32x4;

// ---------------- helpers ----------------

__device__ __forceinline__ unsigned rne_bf16(float f) {
    unsigned u = __builtin_bit_cast(unsigned, f);
    return (u + 0x7FFFu + ((u >> 16) & 1u)) >> 16;
}
__device__ __forceinline__ float bf16lo(unsigned u) {
    return __builtin_bit_cast(float, u << 16);
}
__device__ __forceinline__ float bf16hi(unsigned u) {
    return __builtin_bit_cast(float, u & 0xFFFF0000u);
}
// split x into bf16 hi + bf16 lo (lo captures the next 8 mantissa bits)
__device__ __forceinline__ void split2(float x, unsigned short& h, unsigned short& l) {
    unsigned hu = rne_bf16(x);
    h = (unsigned short)hu;
    l = (unsigned short)rne_bf16(x - bf16lo(hu));
}

// ---------------- CSR build: bucket counting sort (unchanged from round 7) ----------------

__global__ __launch_bounds__(256) void bhist_k(const int* __restrict__ dst,
                                               int* __restrict__ bucketTotal,
                                               int* __restrict__ bhArr) {
    __shared__ int h[NBP];
    int tid = threadIdx.x;
    for (int i = tid; i < NBP; i += 256) h[i] = 0;
    __syncthreads();
#pragma unroll
    for (int c = 0; c < 4; c++) {
        int e = blockIdx.x * 4096 + c * 1024 + tid * 4;
        if (e < N_EDGES) {
            int4 d4 = ((const int4*)dst)[e >> 2];
            atomicAdd(&h[d4.x >> 8], 1);
            atomicAdd(&h[d4.y >> 8], 1);
            atomicAdd(&h[d4.z >> 8], 1);
            atomicAdd(&h[d4.w >> 8], 1);
        }
    }
    __syncthreads();
    for (int i = tid; i < NBP; i += 256) {
        int v = h[i];
        bhArr[blockIdx.x * NBP + i] = v;
        if (v > 0) atomicAdd(&bucketTotal[i], v);
    }
}

__global__ __launch_bounds__(512) void bscan_k(const int* __restrict__ bucketTotal,
                                               int* __restrict__ bucketBase,
                                               int* __restrict__ bucketCursor) {
    __shared__ int tmp[512];
    int tid = threadIdx.x;
    int v = (tid < NBP) ? bucketTotal[tid] : 0;
    tmp[tid] = v;
    __syncthreads();
    for (int off = 1; off < 512; off <<= 1) {
        int x = tmp[tid];
        if (tid >= off) x += tmp[tid - off];
        __syncthreads();
        tmp[tid] = x;
        __syncthreads();
    }
    if (tid < NBP) {
        int excl = tmp[tid] - v;
        bucketBase[tid] = excl;
        bucketCursor[tid] = excl;
        if (tid == NBP - 1) bucketBase[NBP] = tmp[tid];
    }
}

__global__ __launch_bounds__(512) void bscatter_k(const int* __restrict__ src,
                                                  const int* __restrict__ dst,
                                                  const int* __restrict__ bhArr,
                                                  int* __restrict__ bucketCursor,
                                                  int* __restrict__ ebuf) {
    __shared__ int lcur0[NBP];
    __shared__ int pexc[NBP];
    __shared__ int lofs[NBP];
    __shared__ int pfx[512];
    __shared__ int sortedv[4096];
    __shared__ int gaddr[4096];
    int tid = threadIdx.x;
    int bid = blockIdx.x;
    int v = 0;
    if (tid < NBP) {
        v = bhArr[bid * NBP + tid];
        lcur0[tid] = (v > 0) ? atomicAdd(&bucketCursor[tid], v) : 0;
    }
    pfx[tid] = v;
    __syncthreads();
    for (int off = 1; off < 512; off <<= 1) {
        int x = pfx[tid];
        if (tid >= off) x += pfx[tid - off];
        __syncthreads();
        pfx[tid] = x;
        __syncthreads();
    }
    if (tid < NBP) {
        int ex = pfx[tid] - v;
        pexc[tid] = ex;
        lofs[tid] = ex;
    }
    __syncthreads();
#pragma unroll
    for (int c = 0; c < 2; c++) {
        int e = bid * 4096 + c * 2048 + tid * 4;
        if (e < N_EDGES) {
            int4 d4 = ((const int4*)dst)[e >> 2];
            int4 s4 = ((const int4*)src)[e >> 2];
            int b0 = d4.x >> 8, b1 = d4.y >> 8, b2 = d4.z >> 8, b3 = d4.w >> 8;
            int t0 = atomicAdd(&lofs[b0], 1);
            int t1 = atomicAdd(&lofs[b1], 1);
            int t2 = atomicAdd(&lofs[b2], 1);
            int t3 = atomicAdd(&lofs[b3], 1);
            sortedv[t0] = (s4.x << 8) | (d4.x & 255);
            sortedv[t1] = (s4.y << 8) | (d4.y & 255);
            sortedv[t2] = (s4.z << 8) | (d4.z & 255);
            sortedv[t3] = (s4.w << 8) | (d4.w & 255);
            gaddr[t0] = lcur0[b0] + (t0 - pexc[b0]);
            gaddr[t1] = lcur0[b1] + (t1 - pexc[b1]);
            gaddr[t2] = lcur0[b2] + (t2 - pexc[b2]);
            gaddr[t3] = lcur0[b3] + (t3 - pexc[b3]);
        }
    }
    __syncthreads();
    int totalE = min(4096, N_EDGES - bid * 4096);
    for (int j = tid; j < totalE; j += 512)
        ebuf[gaddr[j]] = sortedv[j];
}

__global__ __launch_bounds__(256) void bfinal_k(const int* __restrict__ ebuf,
                                                const int* __restrict__ bucketBase,
                                                int* __restrict__ offsets,
                                                int* __restrict__ nbArr,
                                                int* __restrict__ csr) {
    __shared__ int srt[MAXPAD];
    __shared__ int cnt[256];
    __shared__ int sc[256];
    __shared__ int cur[256];
    int tid = threadIdx.x;
    int b = blockIdx.x;
    int s = bucketBase[b], e = bucketBase[b + 1];
    int m = e - s;
    cnt[tid] = 0;
    __syncthreads();
    for (int i = tid; i < m; i += 256)
        atomicAdd(&cnt[ebuf[s + i] & 255], 1);
    __syncthreads();
    int c = cnt[tid];
    int pad = (c + 3) & ~3;
    sc[tid] = pad;
    __syncthreads();
    for (int off = 1; off < 256; off <<= 1) {
        int x = sc[tid];
        if (tid >= off) x += sc[tid - off];
        __syncthreads();
        sc[tid] = x;
        __syncthreads();
    }
    int pexcl = sc[tid] - pad;
    int gbase = s + b * BSLACK;
    int node = b * 256 + tid;
    if (node < N_NODES) {
        offsets[node] = gbase + pexcl;
        nbArr[node] = pad >> 2;
    }
    cur[tid] = pexcl;
    __syncthreads();
    int padTot = sc[255];
    if (padTot <= MAXPAD) {
        for (int j = tid; j < padTot; j += 256) srt[j] = N_NODES;
        __syncthreads();
        for (int i = tid; i < m; i += 256) {
            int pk = ebuf[s + i];
            int pos = atomicAdd(&cur[pk & 255], 1);
            srt[pos] = (int)((unsigned)pk >> 8);
        }
        __syncthreads();
        for (int j = tid; j < padTot; j += 256)
            csr[gbase + j] = srt[j];
    } else {
        for (int i = tid; i < m; i += 256) {
            int pk = ebuf[s + i];
            int pos = atomicAdd(&cur[pk & 255], 1);
            csr[gbase + pos] = (int)((unsigned)pk >> 8);
        }
        __syncthreads();
        int pend = pexcl + pad;
        for (int p2 = cur[tid]; p2 < pend; p2++) csr[gbase + p2] = N_NODES;
    }
}

// ---------------- per-layer compute ----------------

// prepw (all 3 layers in one launch): W (f32 [128][128]) -> split-bf16
// fragment-linear Wh/Wl. blockIdx = layer*32 + tile; tile t = cb*4 + ks.
// Lane l supplies B-frag: col = cb*16 + (l&15), k = ks*32 + (l>>4)*8 + j.
__global__ __launch_bounds__(64) void prepw_k(const float* __restrict__ W0,
                                              const float* __restrict__ W1,
                                              const float* __restrict__ W2,
                                              unsigned short* __restrict__ wfrag) {
    int l = threadIdx.x;
    int lay = blockIdx.x >> 5;
    int t = blockIdx.x & 31;
    const float* W = (lay == 0) ? W0 : (lay == 1) ? W1 : W2;
    unsigned short* Wh = wfrag + lay * 32768;
    unsigned short* Wl = Wh + 16384;
    int col = ((t >> 2) << 4) + (l & 15);
    int k0 = ((t & 3) << 5) + ((l >> 4) << 3);
    unsigned hw[4], lw[4];
#pragma unroll
    for (int p = 0; p < 4; p++) {
        float x0 = W[(size_t)(k0 + 2 * p) * DIM + col];
        float x1 = W[(size_t)(k0 + 2 * p + 1) * DIM + col];
        unsigned short h0, l0, h1, l1;
        split2(x0, h0, l0);
        split2(x1, h1, l1);
        hw[p] = (unsigned)h0 | ((unsigned)h1 << 16);
        lw[p] = (unsigned)l0 | ((unsigned)l1 << 16);
    }
    size_t base = ((size_t)t * 64 + l) * 8;
    *(uint4*)(Wh + base) = make_uint4(hw[0], hw[1], hw[2], hw[3]);
    *(uint4*)(Wl + base) = make_uint4(lw[0], lw[1], lw[2], lw[3]);
}

// MFMA gemm (layer 1 only), split-bf16: G = bf16(Hh@Wh + Hl@Wh + Hh@Wl).
__global__ __launch_bounds__(256) void gemm_k(const float* __restrict__ H,
                                              const unsigned short* __restrict__ Wh,
                                              const unsigned short* __restrict__ Wl,
                                              unsigned short* __restrict__ G) {
    int tid = threadIdx.x;
    int l = tid & 63;
    int wv = tid >> 6;
    int rowBase = blockIdx.x * 64 + wv * 16;
    int r = rowBase + (l & 15);
    int kg = (l >> 4) << 3;
    const float* hp = H + (size_t)((r < N_NODES) ? r : 0) * DIM;
    float zmask = (r < N_NODES) ? 1.0f : 0.0f;

    f32x4 acc[8];
#pragma unroll
    for (int cb = 0; cb < 8; cb++) acc[cb] = (f32x4){0.f, 0.f, 0.f, 0.f};

#pragma unroll
    for (int ks = 0; ks < 4; ks++) {
        float4 u0 = *(const float4*)(hp + ks * 32 + kg);
        float4 u1 = *(const float4*)(hp + ks * 32 + kg + 4);
        short8 ah, al;
        unsigned short hh, ll;
        split2(u0.x * zmask, hh, ll); ah[0] = hh; al[0] = ll;
        split2(u0.y * zmask, hh, ll); ah[1] = hh; al[1] = ll;
        split2(u0.z * zmask, hh, ll); ah[2] = hh; al[2] = ll;
        split2(u0.w * zmask, hh, ll); ah[3] = hh; al[3] = ll;
        split2(u1.x * zmask, hh, ll); ah[4] = hh; al[4] = ll;
        split2(u1.y * zmask, hh, ll); ah[5] = hh; al[5] = ll;
        split2(u1.z * zmask, hh, ll); ah[6] = hh; al[6] = ll;
        split2(u1.w * zmask, hh, ll); ah[7] = hh; al[7] = ll;
#pragma unroll
        for (int cb = 0; cb < 8; cb++) {
            size_t fidx = (size_t)((cb * 4 + ks) * 64 + l) * 8;
            short8 bh = *(const short8*)(Wh + fidx);
            short8 bl = *(const short8*)(Wl + fidx);
            acc[cb] = __builtin_amdgcn_mfma_f32_16x16x32_bf16(ah, bh, acc[cb], 0, 0, 0);
            acc[cb] = __builtin_amdgcn_mfma_f32_16x16x32_bf16(al, bh, acc[cb], 0, 0, 0);
            acc[cb] = __builtin_amdgcn_mfma_f32_16x16x32_bf16(ah, bl, acc[cb], 0, 0, 0);
        }
    }

    int ro = rowBase + ((l >> 4) << 2);
    int co = l & 15;
#pragma unroll
    for (int cb = 0; cb < 8; cb++) {
#pragma unroll
        for (int j = 0; j < 4; j++) {
            int rr = ro + j;
            if (rr <= N_NODES)
                G[(size_t)rr * DIM + cb * 16 + co] = (unsigned short)rne_bf16(acc[cb][j]);
        }
    }
}

__device__ __forceinline__ void accum8(float* acc, uint4 v) {
    acc[0] += bf16lo(v.x); acc[1] += bf16hi(v.x);
    acc[2] += bf16lo(v.y); acc[3] += bf16hi(v.y);
    acc[4] += bf16lo(v.z); acc[5] += bf16hi(v.z);
    acc[6] += bf16lo(v.w); acc[7] += bf16hi(v.w);
}

// FUSED agg_l + gemm_{l+1}. Round-10 change: h' is staged in LDS as PRE-SPLIT
// bf16 A-fragments (aHi/aLo, fragment-linear), not f32. The gather epilogue
// splits its 8 h'-values ONCE and writes two uint4s at slot
// idx = (q>>2)*64 + (q&3)*16 + wid  (= ks*64 + mfma_lane for row wid,
// k = q*8..q*8+7). Kills the 8x-redundant split2 in the old MFMA phase
// (16K split2/block -> 2K) and the 2.0M bank conflicts (scalar f32 reads ->
// stride-1 ds_read_b128). Split values & MFMA order unchanged -> bit-identical.
__global__ __launch_bounds__(1024) void aggemm_k(const unsigned short* __restrict__ G,
                                                 const int* __restrict__ off,
                                                 const int* __restrict__ nbArr,
                                                 const int* __restrict__ csr,
                                                 const float* __restrict__ bias,
                                                 const float* __restrict__ epsp,
                                                 const unsigned short* __restrict__ Wh,
                                                 const unsigned short* __restrict__ Wl,
                                                 unsigned short* __restrict__ Gout) {
    __shared__ uint4 aHi[256];   // [ks][mfma_lane] packed bf16-hi A-fragments
    __shared__ uint4 aLo[256];   // [ks][mfma_lane] packed bf16-lo
    int tid = threadIdx.x;
    int lane = tid & 63;
    int wid = tid >> 6;              // 0..15 = node slot
    int node = blockIdx.x * 16 + wid;
    int quarter = lane >> 4;
    int q = lane & 15;
    float e1 = 1.0f + epsp[0];

    // ---- gather phase (identical math/order to agg_k) ----
    int offA = off[node];
    int nb = nbArr[node];
    const int* clb = csr + offA + quarter;
    float acc[8] = {0.f, 0.f, 0.f, 0.f, 0.f, 0.f, 0.f, 0.f};
    int b = 0;
    for (; b + 4 <= nb; b += 4) {
        int i0 = clb[0];
        int i1 = clb[4];
        int i2 = clb[8];
        int i3 = clb[12];
        clb += 16;
        uint4 g0 = *(const uint4*)(G + (size_t)i0 * DIM + q * 8);
        uint4 g1 = *(const uint4*)(G + (size_t)i1 * DIM + q * 8);
        uint4 g2 = *(const uint4*)(G + (size_t)i2 * DIM + q * 8);
        uint4 g3 = *(const uint4*)(G + (size_t)i3 * DIM + q * 8);
        accum8(acc, g0);
        accum8(acc, g1);
        accum8(acc, g2);
        accum8(acc, g3);
    }
    for (; b < nb; b++) {
        int i0 = clb[0];
        clb += 4;
        uint4 g0 = *(const uint4*)(G + (size_t)i0 * DIM + q * 8);
        accum8(acc, g0);
    }
#pragma unroll
    for (int j = 0; j < 8; j++) {
        acc[j] += __shfl_xor(acc[j], 16);
        acc[j] += __shfl_xor(acc[j], 32);
    }
    if (quarter == 0) {
        uint4 sv = *(const uint4*)(G + (size_t)node * DIM + q * 8);
        float4 b0 = *(const float4*)(bias + q * 8);
        float4 b1 = *(const float4*)(bias + q * 8 + 4);
        float hv[8];
        hv[0] = acc[0] + e1 * bf16lo(sv.x) + b0.x;
        hv[1] = acc[1] + e1 * bf16hi(sv.x) + b0.y;
        hv[2] = acc[2] + e1 * bf16lo(sv.y) + b0.z;
        hv[3] = acc[3] + e1 * bf16hi(sv.y) + b0.w;
        hv[4] = acc[4] + e1 * bf16lo(sv.z) + b1.x;
        hv[5] = acc[5] + e1 * bf16hi(sv.z) + b1.y;
        hv[6] = acc[6] + e1 * bf16lo(sv.w) + b1.z;
        hv[7] = acc[7] + e1 * bf16hi(sv.w) + b1.w;
        unsigned hp[4], lp[4];
#pragma unroll
        for (int p = 0; p < 4; p++) {
            unsigned short h0, l0, h1, l1;
            split2(hv[2 * p], h0, l0);
            split2(hv[2 * p + 1], h1, l1);
            hp[p] = (unsigned)h0 | ((unsigned)h1 << 16);
            lp[p] = (unsigned)l0 | ((unsigned)l1 << 16);
        }
        int idx = ((q >> 2) << 6) + ((q & 3) << 4) + wid;   // ks*64 + mfma_lane
        aHi[idx] = make_uint4(hp[0], hp[1], hp[2], hp[3]);
        aLo[idx] = make_uint4(lp[0], lp[1], lp[2], lp[3]);
    }
    __syncthreads();

    // ---- MFMA phase: waves 0..7, one 16-col block each; A pre-split in LDS ----
    if (wid < 8) {
        int cb = wid;
        f32x4 o = (f32x4){0.f, 0.f, 0.f, 0.f};
#pragma unroll
        for (int ks = 0; ks < 4; ks++) {
            short8 ah = *(const short8*)&aHi[ks * 64 + lane];
            short8 al = *(const short8*)&aLo[ks * 64 + lane];
            size_t fidx = (size_t)((cb * 4 + ks) * 64 + lane) * 8;
            short8 bh = *(const short8*)(Wh + fidx);
            short8 bl = *(const short8*)(Wl + fidx);
            o = __builtin_amdgcn_mfma_f32_16x16x32_bf16(ah, bh, o, 0, 0, 0);
            o = __builtin_amdgcn_mfma_f32_16x16x32_bf16(al, bh, o, 0, 0, 0);
            o = __builtin_amdgcn_mfma_f32_16x16x32_bf16(ah, bl, o, 0, 0, 0);
        }
        int ro = blockIdx.x * 16 + ((lane >> 4) << 2);
        int co = cb * 16 + (lane & 15);
#pragma unroll
        for (int j = 0; j < 4; j++)
            Gout[(size_t)(ro + j) * DIM + co] = (unsigned short)rne_bf16(o[j]);
    } else if (wid == 8 && blockIdx.x == 0) {
        // sentinel row of Gout = zeros (read by next layer's gather padding)
        ((unsigned*)(Gout + (size_t)N_NODES * DIM))[lane] = 0u;
    }
}

// Ungrouped full-row gather (structural floor ~108us). FROZEN. Final layer only.
__global__ __launch_bounds__(256) void agg_k(const unsigned short* __restrict__ G,
                                             const int* __restrict__ off,
                                             const int* __restrict__ nbArr,
                                             const int* __restrict__ csr,
                                             const float* __restrict__ bias,
                                             const float* __restrict__ epsp,
                                             float* __restrict__ out) {
    int tid = threadIdx.x;
    int lane = tid & 63;
    int node = blockIdx.x * 4 + (tid >> 6);
    int quarter = lane >> 4;
    int q = lane & 15;
    float e1 = 1.0f + epsp[0];

    int offA = off[node];
    int nb = nbArr[node];
    const int* clb = csr + offA + quarter;

    float acc[8] = {0.f, 0.f, 0.f, 0.f, 0.f, 0.f, 0.f, 0.f};

    int b = 0;
    for (; b + 4 <= nb; b += 4) {
        int i0 = clb[0];
        int i1 = clb[4];
        int i2 = clb[8];
        int i3 = clb[12];
        clb += 16;
        uint4 g0 = *(const uint4*)(G + (size_t)i0 * DIM + q * 8);
        uint4 g1 = *(const uint4*)(G + (size_t)i1 * DIM + q * 8);
        uint4 g2 = *(const uint4*)(G + (size_t)i2 * DIM + q * 8);
        uint4 g3 = *(const uint4*)(G + (size_t)i3 * DIM + q * 8);
        accum8(acc, g0);
        accum8(acc, g1);
        accum8(acc, g2);
        accum8(acc, g3);
    }
    for (; b < nb; b++) {
        int i0 = clb[0];
        clb += 4;
        uint4 g0 = *(const uint4*)(G + (size_t)i0 * DIM + q * 8);
        accum8(acc, g0);
    }

#pragma unroll
    for (int j = 0; j < 8; j++) {
        acc[j] += __shfl_xor(acc[j], 16);
        acc[j] += __shfl_xor(acc[j], 32);
    }

    if (quarter == 0) {
        uint4 sv = *(const uint4*)(G + (size_t)node * DIM + q * 8);
        float4 b0 = *(const float4*)(bias + q * 8);
        float4 b1 = *(const float4*)(bias + q * 8 + 4);
        float* op = out + (size_t)node * DIM + q * 8;
        float4 r0, r1;
        r0.x = acc[0] + e1 * bf16lo(sv.x) + b0.x;
        r0.y = acc[1] + e1 * bf16hi(sv.x) + b0.y;
        r0.z = acc[2] + e1 * bf16lo(sv.y) + b0.z;
        r0.w = acc[3] + e1 * bf16hi(sv.y) + b0.w;
        r1.x = acc[4] + e1 * bf16lo(sv.z) + b1.x;
        r1.y = acc[5] + e1 * bf16hi(sv.z) + b1.y;
        r1.z = acc[6] + e1 * bf16lo(sv.w) + b1.z;
        r1.w = acc[7] + e1 * bf16hi(sv.w) + b1.w;
        *(float4*)op = r0;
        *(float4*)(op + 4) = r1;
    }
}

// ---------------- launch ----------------

extern "C" void kernel_launch(void* const* d_in, const int* in_sizes, int n_in,
                              void* d_out, int out_size, void* d_ws, size_t ws_size,
                              hipStream_t stream) {
    const float* feats = (const float*)d_in[0];
    const int* esrc = (const int*)d_in[1];
    const int* edst = (const int*)d_in[2];
    const float* Wm[3] = {(const float*)d_in[3], (const float*)d_in[6], (const float*)d_in[9]};
    const float* Bv[3] = {(const float*)d_in[4], (const float*)d_in[7], (const float*)d_in[10]};
    const float* Ev[3] = {(const float*)d_in[5], (const float*)d_in[8], (const float*)d_in[11]};
    float* out = (float*)d_out;

    char* ws = (char*)d_ws;
    unsigned short* bufG = (unsigned short*)(ws);        // 25,600,256 B : [100001][128] bf16 (G_A)
    int* ebuf       = (int*)(ws + 25600512);             // 12,800,000 B packed (src<<8|dst&255)
    int* csr        = (int*)(ws + 38400512);             // 16,003,072 B padded csr
    int* offsets    = (int*)(ws + 54411776);             //    400,000 B
    int* nbArr      = (int*)(ws + 54811776);             //    400,000 B
    int* bucketTotal= (int*)(ws + 55211776);             //      1,568 B
    int* bucketBase = (int*)(ws + 55213376);             //      1,572 B
    int* bucketCur  = (int*)(ws + 55215040);             //      1,568 B
    int* bhArr      = (int*)(ws + 55216640);             //  1,226,176 B per-block bucket hists
    unsigned short* wfrag = (unsigned short*)(ws + 56442816);  // 6 x 32,768 B: Wh0,Wl0,Wh1,Wl1,Wh2,Wl2

    unsigned short* G_A = bufG;
    unsigned short* G_B = (unsigned short*)d_out;  // 25.6MB bf16 scratch inside the 51.2MB
                                                   // output buffer; dead before agg3 overwrites out

    // W fragment prep (split-bf16, fragment-linear), all 3 layers in one launch
    prepw_k<<<96, 64, 0, stream>>>(Wm[0], Wm[1], Wm[2], wfrag);

    // CSR build: bucket counting sort (stores de-scattered via LDS reordering)
    hipMemsetAsync(bucketTotal, 0, NBP * sizeof(int), stream);
    bhist_k<<<EB_BLOCKS, 256, 0, stream>>>(edst, bucketTotal, bhArr);
    bscan_k<<<1, 512, 0, stream>>>(bucketTotal, bucketBase, bucketCur);
    bscatter_k<<<EB_BLOCKS, 512, 0, stream>>>(esrc, edst, bhArr, bucketCur, ebuf);
    bfinal_k<<<NBUCK, 256, 0, stream>>>(ebuf, bucketBase, offsets, nbArr, csr);

    // layer 1 gemm: G_A = bf16(feats @ W0)
    gemm_k<<<(N_NODES + 64) / 64, 256, 0, stream>>>(feats, wfrag, wfrag + 16384, G_A);
    // fused agg1+gemm2: G_B = bf16(h1' @ W1)
    aggemm_k<<<N_NODES / 16, 1024, 0, stream>>>(G_A, offsets, nbArr, csr, Bv[0], Ev[0],
                                                wfrag + 32768, wfrag + 49152, G_B);
    // fused agg2+gemm3: G_A = bf16(h2' @ W2)
    aggemm_k<<<N_NODES / 16, 1024, 0, stream>>>(G_B, offsets, nbArr, csr, Bv[1], Ev[1],
                                                wfrag + 65536, wfrag + 81920, G_A);
    // final agg: out = (1+eps)g3 + agg(g3) + b3  (f32)
    agg_k<<<N_NODES / 4, 256, 0, stream>>>(G_A, offsets, nbArr, csr, Bv[2], Ev[2], out);
}

// Round 11
// 553.626 us; speedup vs baseline: 1.5068x; 1.0042x over previous
//
#include <hip/hip_runtime.h>

#define N_NODES 100000
#define N_EDGES 3200000
#define DIM 128
#define GROWS (N_NODES + 1)   // +1: sentinel all-zero row for csr padding
#define NBUCK 391        // ceil(100000/256) buckets of 256 nodes (dst>>8)
#define NBP 392          // padded
#define EB_BLOCKS 782    // ceil(3.2M / 4096) edge blocks (4096 edges/block)
#define BSLACK 2048      // per-bucket csr padding slack (>= 256 nodes * 3)
#define MAXPAD 9984      // LDS cap for one bucket's PADDED csr segment (mean ~8.6K, +15 sigma)

typedef __attribute__((ext_vector_type(8))) short short8;
typedef __attribute__((ext_vector_type(4))) float f32x4;

// ---------------- helpers ----------------

__device__ __forceinline__ unsigned rne_bf16(float f) {
    unsigned u = __builtin_bit_cast(unsigned, f);
    return (u + 0x7FFFu + ((u >> 16) & 1u)) >> 16;
}
__device__ __forceinline__ float bf16lo(unsigned u) {
    return __builtin_bit_cast(float, u << 16);
}
__device__ __forceinline__ float bf16hi(unsigned u) {
    return __builtin_bit_cast(float, u & 0xFFFF0000u);
}
// split x into bf16 hi + bf16 lo (lo captures the next 8 mantissa bits)
__device__ __forceinline__ void split2(float x, unsigned short& h, unsigned short& l) {
    unsigned hu = rne_bf16(x);
    h = (unsigned short)hu;
    l = (unsigned short)rne_bf16(x - bf16lo(hu));
}

// ---------------- CSR build: bucket counting sort (unchanged from round 7) ----------------

__global__ __launch_bounds__(256) void bhist_k(const int* __restrict__ dst,
                                               int* __restrict__ bucketTotal,
                                               int* __restrict__ bhArr) {
    __shared__ int h[NBP];
    int tid = threadIdx.x;
    for (int i = tid; i < NBP; i += 256) h[i] = 0;
    __syncthreads();
#pragma unroll
    for (int c = 0; c < 4; c++) {
        int e = blockIdx.x * 4096 + c * 1024 + tid * 4;
        if (e < N_EDGES) {
            int4 d4 = ((const int4*)dst)[e >> 2];
            atomicAdd(&h[d4.x >> 8], 1);
            atomicAdd(&h[d4.y >> 8], 1);
            atomicAdd(&h[d4.z >> 8], 1);
            atomicAdd(&h[d4.w >> 8], 1);
        }
    }
    __syncthreads();
    for (int i = tid; i < NBP; i += 256) {
        int v = h[i];
        bhArr[blockIdx.x * NBP + i] = v;
        if (v > 0) atomicAdd(&bucketTotal[i], v);
    }
}

__global__ __launch_bounds__(512) void bscan_k(const int* __restrict__ bucketTotal,
                                               int* __restrict__ bucketBase,
                                               int* __restrict__ bucketCursor) {
    __shared__ int tmp[512];
    int tid = threadIdx.x;
    int v = (tid < NBP) ? bucketTotal[tid] : 0;
    tmp[tid] = v;
    __syncthreads();
    for (int off = 1; off < 512; off <<= 1) {
        int x = tmp[tid];
        if (tid >= off) x += tmp[tid - off];
        __syncthreads();
        tmp[tid] = x;
        __syncthreads();
    }
    if (tid < NBP) {
        int excl = tmp[tid] - v;
        bucketBase[tid] = excl;
        bucketCursor[tid] = excl;
        if (tid == NBP - 1) bucketBase[NBP] = tmp[tid];
    }
}

__global__ __launch_bounds__(512) void bscatter_k(const int* __restrict__ src,
                                                  const int* __restrict__ dst,
                                                  const int* __restrict__ bhArr,
                                                  int* __restrict__ bucketCursor,
                                                  int* __restrict__ ebuf) {
    __shared__ int lcur0[NBP];
    __shared__ int pexc[NBP];
    __shared__ int lofs[NBP];
    __shared__ int pfx[512];
    __shared__ int sortedv[4096];
    __shared__ int gaddr[4096];
    int tid = threadIdx.x;
    int bid = blockIdx.x;
    int v = 0;
    if (tid < NBP) {
        v = bhArr[bid * NBP + tid];
        lcur0[tid] = (v > 0) ? atomicAdd(&bucketCursor[tid], v) : 0;
    }
    pfx[tid] = v;
    __syncthreads();
    for (int off = 1; off < 512; off <<= 1) {
        int x = pfx[tid];
        if (tid >= off) x += pfx[tid - off];
        __syncthreads();
        pfx[tid] = x;
        __syncthreads();
    }
    if (tid < NBP) {
        int ex = pfx[tid] - v;
        pexc[tid] = ex;
        lofs[tid] = ex;
    }
    __syncthreads();
#pragma unroll
    for (int c = 0; c < 2; c++) {
        int e = bid * 4096 + c * 2048 + tid * 4;
        if (e < N_EDGES) {
            int4 d4 = ((const int4*)dst)[e >> 2];
            int4 s4 = ((const int4*)src)[e >> 2];
            int b0 = d4.x >> 8, b1 = d4.y >> 8, b2 = d4.z >> 8, b3 = d4.w >> 8;
            int t0 = atomicAdd(&lofs[b0], 1);
            int t1 = atomicAdd(&lofs[b1], 1);
            int t2 = atomicAdd(&lofs[b2], 1);
            int t3 = atomicAdd(&lofs[b3], 1);
            sortedv[t0] = (s4.x << 8) | (d4.x & 255);
            sortedv[t1] = (s4.y << 8) | (d4.y & 255);
            sortedv[t2] = (s4.z << 8) | (d4.z & 255);
            sortedv[t3] = (s4.w << 8) | (d4.w & 255);
            gaddr[t0] = lcur0[b0] + (t0 - pexc[b0]);
            gaddr[t1] = lcur0[b1] + (t1 - pexc[b1]);
            gaddr[t2] = lcur0[b2] + (t2 - pexc[b2]);
            gaddr[t3] = lcur0[b3] + (t3 - pexc[b3]);
        }
    }
    __syncthreads();
    int totalE = min(4096, N_EDGES - bid * 4096);
    for (int j = tid; j < totalE; j += 512)
        ebuf[gaddr[j]] = sortedv[j];
}

__global__ __launch_bounds__(256) void bfinal_k(const int* __restrict__ ebuf,
                                                const int* __restrict__ bucketBase,
                                                int* __restrict__ offsets,
                                                int* __restrict__ nbArr,
                                                int* __restrict__ csr) {
    __shared__ int srt[MAXPAD];
    __shared__ int cnt[256];
    __shared__ int sc[256];
    __shared__ int cur[256];
    int tid = threadIdx.x;
    int b = blockIdx.x;
    int s = bucketBase[b], e = bucketBase[b + 1];
    int m = e - s;
    cnt[tid] = 0;
    __syncthreads();
    for (int i = tid; i < m; i += 256)
        atomicAdd(&cnt[ebuf[s + i] & 255], 1);
    __syncthreads();
    int c = cnt[tid];
    int pad = (c + 3) & ~3;
    sc[tid] = pad;
    __syncthreads();
    for (int off = 1; off < 256; off <<= 1) {
        int x = sc[tid];
        if (tid >= off) x += sc[tid - off];
        __syncthreads();
        sc[tid] = x;
        __syncthreads();
    }
    int pexcl = sc[tid] - pad;
    int gbase = s + b * BSLACK;
    int node = b * 256 + tid;
    if (node < N_NODES) {
        offsets[node] = gbase + pexcl;
        nbArr[node] = pad >> 2;
    }
    cur[tid] = pexcl;
    __syncthreads();
    int padTot = sc[255];
    if (padTot <= MAXPAD) {
        for (int j = tid; j < padTot; j += 256) srt[j] = N_NODES;
        __syncthreads();
        for (int i = tid; i < m; i += 256) {
            int pk = ebuf[s + i];
            int pos = atomicAdd(&cur[pk & 255], 1);
            srt[pos] = (int)((unsigned)pk >> 8);
        }
        __syncthreads();
        for (int j = tid; j < padTot; j += 256)
            csr[gbase + j] = srt[j];
    } else {
        for (int i = tid; i < m; i += 256) {
            int pk = ebuf[s + i];
            int pos = atomicAdd(&cur[pk & 255], 1);
            csr[gbase + pos] = (int)((unsigned)pk >> 8);
        }
        __syncthreads();
        int pend = pexcl + pad;
        for (int p2 = cur[tid]; p2 < pend; p2++) csr[gbase + p2] = N_NODES;
    }
}

// ---------------- per-layer compute ----------------

// prepw (all 3 layers in one launch): W (f32 [128][128]) -> split-bf16
// fragment-linear Wh/Wl. blockIdx = layer*32 + tile; tile t = cb*4 + ks.
// Lane l supplies B-frag: col = cb*16 + (l&15), k = ks*32 + (l>>4)*8 + j.
__global__ __launch_bounds__(64) void prepw_k(const float* __restrict__ W0,
                                              const float* __restrict__ W1,
                                              const float* __restrict__ W2,
                                              unsigned short* __restrict__ wfrag) {
    int l = threadIdx.x;
    int lay = blockIdx.x >> 5;
    int t = blockIdx.x & 31;
    const float* W = (lay == 0) ? W0 : (lay == 1) ? W1 : W2;
    unsigned short* Wh = wfrag + lay * 32768;
    unsigned short* Wl = Wh + 16384;
    int col = ((t >> 2) << 4) + (l & 15);
    int k0 = ((t & 3) << 5) + ((l >> 4) << 3);
    unsigned hw[4], lw[4];
#pragma unroll
    for (int p = 0; p < 4; p++) {
        float x0 = W[(size_t)(k0 + 2 * p) * DIM + col];
        float x1 = W[(size_t)(k0 + 2 * p + 1) * DIM + col];
        unsigned short h0, l0, h1, l1;
        split2(x0, h0, l0);
        split2(x1, h1, l1);
        hw[p] = (unsigned)h0 | ((unsigned)h1 << 16);
        lw[p] = (unsigned)l0 | ((unsigned)l1 << 16);
    }
    size_t base = ((size_t)t * 64 + l) * 8;
    *(uint4*)(Wh + base) = make_uint4(hw[0], hw[1], hw[2], hw[3]);
    *(uint4*)(Wl + base) = make_uint4(lw[0], lw[1], lw[2], lw[3]);
}

// MFMA gemm (layer 1 only), split-bf16: G = bf16(Hh@Wh + Hl@Wh + Hh@Wl).
__global__ __launch_bounds__(256) void gemm_k(const float* __restrict__ H,
                                              const unsigned short* __restrict__ Wh,
                                              const unsigned short* __restrict__ Wl,
                                              unsigned short* __restrict__ G) {
    int tid = threadIdx.x;
    int l = tid & 63;
    int wv = tid >> 6;
    int rowBase = blockIdx.x * 64 + wv * 16;
    int r = rowBase + (l & 15);
    int kg = (l >> 4) << 3;
    const float* hp = H + (size_t)((r < N_NODES) ? r : 0) * DIM;
    float zmask = (r < N_NODES) ? 1.0f : 0.0f;

    f32x4 acc[8];
#pragma unroll
    for (int cb = 0; cb < 8; cb++) acc[cb] = (f32x4){0.f, 0.f, 0.f, 0.f};

#pragma unroll
    for (int ks = 0; ks < 4; ks++) {
        float4 u0 = *(const float4*)(hp + ks * 32 + kg);
        float4 u1 = *(const float4*)(hp + ks * 32 + kg + 4);
        short8 ah, al;
        unsigned short hh, ll;
        split2(u0.x * zmask, hh, ll); ah[0] = hh; al[0] = ll;
        split2(u0.y * zmask, hh, ll); ah[1] = hh; al[1] = ll;
        split2(u0.z * zmask, hh, ll); ah[2] = hh; al[2] = ll;
        split2(u0.w * zmask, hh, ll); ah[3] = hh; al[3] = ll;
        split2(u1.x * zmask, hh, ll); ah[4] = hh; al[4] = ll;
        split2(u1.y * zmask, hh, ll); ah[5] = hh; al[5] = ll;
        split2(u1.z * zmask, hh, ll); ah[6] = hh; al[6] = ll;
        split2(u1.w * zmask, hh, ll); ah[7] = hh; al[7] = ll;
#pragma unroll
        for (int cb = 0; cb < 8; cb++) {
            size_t fidx = (size_t)((cb * 4 + ks) * 64 + l) * 8;
            short8 bh = *(const short8*)(Wh + fidx);
            short8 bl = *(const short8*)(Wl + fidx);
            acc[cb] = __builtin_amdgcn_mfma_f32_16x16x32_bf16(ah, bh, acc[cb], 0, 0, 0);
            acc[cb] = __builtin_amdgcn_mfma_f32_16x16x32_bf16(al, bh, acc[cb], 0, 0, 0);
            acc[cb] = __builtin_amdgcn_mfma_f32_16x16x32_bf16(ah, bl, acc[cb], 0, 0, 0);
        }
    }

    int ro = rowBase + ((l >> 4) << 2);
    int co = l & 15;
#pragma unroll
    for (int cb = 0; cb < 8; cb++) {
#pragma unroll
        for (int j = 0; j < 4; j++) {
            int rr = ro + j;
            if (rr <= N_NODES)
                G[(size_t)rr * DIM + cb * 16 + co] = (unsigned short)rne_bf16(acc[cb][j]);
        }
    }
}

__device__ __forceinline__ void accum8(float* acc, uint4 v) {
    acc[0] += bf16lo(v.x); acc[1] += bf16hi(v.x);
    acc[2] += bf16lo(v.y); acc[3] += bf16hi(v.y);
    acc[4] += bf16lo(v.z); acc[5] += bf16hi(v.z);
    acc[6] += bf16lo(v.w); acc[7] += bf16hi(v.w);
}

// FUSED agg_l + gemm_{l+1}, v3 (round 11):
//  - 512 thr = 8 waves, still 16 nodes/block: each wave gathers 2 nodes
//    SEQUENTIALLY (no intra-wave padding waste), then ALL 8 waves run the
//    MFMA phase (was: 16 waves, half idle in MFMA; 2 blocks/CU -> now 4).
//  - A-fragment LDS: ks-row stride 66 uint4 (264B -> 8*ks bank rotation) +
//    XOR swizzle g(l) = l ^ ((l>>4)&3) on write AND read. Old layout was a
//    structural 16-way write conflict (slot%8 == wid for all 16 lanes ->
//    2.8M conflict cycles); now max 2-way (free).
// Split values & MFMA order unchanged -> bit-identical output.
__global__ __launch_bounds__(512) void aggemm_k(const unsigned short* __restrict__ G,
                                                 const int* __restrict__ off,
                                                 const int* __restrict__ nbArr,
                                                 const int* __restrict__ csr,
                                                 const float* __restrict__ bias,
                                                 const float* __restrict__ epsp,
                                                 const unsigned short* __restrict__ Wh,
                                                 const unsigned short* __restrict__ Wl,
                                                 unsigned short* __restrict__ Gout) {
    __shared__ uint4 aHi[4 * 66];   // [ks][swizzled mfma_lane], padded stride 66
    __shared__ uint4 aLo[4 * 66];
    int tid = threadIdx.x;
    int lane = tid & 63;
    int w = tid >> 6;                // 0..7
    int quarter = lane >> 4;
    int q = lane & 15;
    float e1 = 1.0f + epsp[0];

    // ---- gather phase: 2 nodes per wave, sequential (identical math to agg_k) ----
#pragma unroll
    for (int half = 0; half < 2; half++) {
        int wid = w * 2 + half;          // row slot 0..15
        int node = blockIdx.x * 16 + wid;
        int offA = off[node];
        int nb = nbArr[node];
        const int* clb = csr + offA + quarter;
        float acc[8] = {0.f, 0.f, 0.f, 0.f, 0.f, 0.f, 0.f, 0.f};
        int b = 0;
        for (; b + 4 <= nb; b += 4) {
            int i0 = clb[0];
            int i1 = clb[4];
            int i2 = clb[8];
            int i3 = clb[12];
            clb += 16;
            uint4 g0 = *(const uint4*)(G + (size_t)i0 * DIM + q * 8);
            uint4 g1 = *(const uint4*)(G + (size_t)i1 * DIM + q * 8);
            uint4 g2 = *(const uint4*)(G + (size_t)i2 * DIM + q * 8);
            uint4 g3 = *(const uint4*)(G + (size_t)i3 * DIM + q * 8);
            accum8(acc, g0);
            accum8(acc, g1);
            accum8(acc, g2);
            accum8(acc, g3);
        }
        for (; b < nb; b++) {
            int i0 = clb[0];
            clb += 4;
            uint4 g0 = *(const uint4*)(G + (size_t)i0 * DIM + q * 8);
            accum8(acc, g0);
        }
#pragma unroll
        for (int j = 0; j < 8; j++) {
            acc[j] += __shfl_xor(acc[j], 16);
            acc[j] += __shfl_xor(acc[j], 32);
        }
        if (quarter == 0) {
            uint4 sv = *(const uint4*)(G + (size_t)node * DIM + q * 8);
            float4 b0 = *(const float4*)(bias + q * 8);
            float4 b1 = *(const float4*)(bias + q * 8 + 4);
            float hv[8];
            hv[0] = acc[0] + e1 * bf16lo(sv.x) + b0.x;
            hv[1] = acc[1] + e1 * bf16hi(sv.x) + b0.y;
            hv[2] = acc[2] + e1 * bf16lo(sv.y) + b0.z;
            hv[3] = acc[3] + e1 * bf16hi(sv.y) + b0.w;
            hv[4] = acc[4] + e1 * bf16lo(sv.z) + b1.x;
            hv[5] = acc[5] + e1 * bf16hi(sv.z) + b1.y;
            hv[6] = acc[6] + e1 * bf16lo(sv.w) + b1.z;
            hv[7] = acc[7] + e1 * bf16hi(sv.w) + b1.w;
            unsigned hp[4], lp[4];
#pragma unroll
            for (int p = 0; p < 4; p++) {
                unsigned short h0, l0, h1, l1;
                split2(hv[2 * p], h0, l0);
                split2(hv[2 * p + 1], h1, l1);
                hp[p] = (unsigned)h0 | ((unsigned)h1 << 16);
                lp[p] = (unsigned)l0 | ((unsigned)l1 << 16);
            }
            int l_ = ((q & 3) << 4) + wid;            // mfma lane for (row,k-slice)
            int gsw = l_ ^ ((l_ >> 4) & 3);           // XOR swizzle
            int idx = (q >> 2) * 66 + gsw;            // ks-row stride 66
            aHi[idx] = make_uint4(hp[0], hp[1], hp[2], hp[3]);
            aLo[idx] = make_uint4(lp[0], lp[1], lp[2], lp[3]);
        }
    }
    __syncthreads();

    // ---- MFMA phase: ALL 8 waves, wave w = col-block cb ----
    {
        int cb = w;
        int gl = lane ^ ((lane >> 4) & 3);            // same swizzle on read
        f32x4 o = (f32x4){0.f, 0.f, 0.f, 0.f};
#pragma unroll
        for (int ks = 0; ks < 4; ks++) {
            short8 ah = *(const short8*)&aHi[ks * 66 + gl];
            short8 al = *(const short8*)&aLo[ks * 66 + gl];
            size_t fidx = (size_t)((cb * 4 + ks) * 64 + lane) * 8;
            short8 bh = *(const short8*)(Wh + fidx);
            short8 bl = *(const short8*)(Wl + fidx);
            o = __builtin_amdgcn_mfma_f32_16x16x32_bf16(ah, bh, o, 0, 0, 0);
            o = __builtin_amdgcn_mfma_f32_16x16x32_bf16(al, bh, o, 0, 0, 0);
            o = __builtin_amdgcn_mfma_f32_16x16x32_bf16(ah, bl, o, 0, 0, 0);
        }
        int ro = blockIdx.x * 16 + ((lane >> 4) << 2);
        int co = cb * 16 + (lane & 15);
#pragma unroll
        for (int j = 0; j < 4; j++)
            Gout[(size_t)(ro + j) * DIM + co] = (unsigned short)rne_bf16(o[j]);
    }
    if (blockIdx.x == 0 && w == 0) {
        // sentinel row of Gout = zeros (read by next layer's gather padding)
        ((unsigned*)(Gout + (size_t)N_NODES * DIM))[lane] = 0u;
    }
}

// Ungrouped full-row gather (structural floor ~108us). FROZEN. Final layer only.
__global__ __launch_bounds__(256) void agg_k(const unsigned short* __restrict__ G,
                                             const int* __restrict__ off,
                                             const int* __restrict__ nbArr,
                                             const int* __restrict__ csr,
                                             const float* __restrict__ bias,
                                             const float* __restrict__ epsp,
                                             float* __restrict__ out) {
    int tid = threadIdx.x;
    int lane = tid & 63;
    int node = blockIdx.x * 4 + (tid >> 6);
    int quarter = lane >> 4;
    int q = lane & 15;
    float e1 = 1.0f + epsp[0];

    int offA = off[node];
    int nb = nbArr[node];
    const int* clb = csr + offA + quarter;

    float acc[8] = {0.f, 0.f, 0.f, 0.f, 0.f, 0.f, 0.f, 0.f};

    int b = 0;
    for (; b + 4 <= nb; b += 4) {
        int i0 = clb[0];
        int i1 = clb[4];
        int i2 = clb[8];
        int i3 = clb[12];
        clb += 16;
        uint4 g0 = *(const uint4*)(G + (size_t)i0 * DIM + q * 8);
        uint4 g1 = *(const uint4*)(G + (size_t)i1 * DIM + q * 8);
        uint4 g2 = *(const uint4*)(G + (size_t)i2 * DIM + q * 8);
        uint4 g3 = *(const uint4*)(G + (size_t)i3 * DIM + q * 8);
        accum8(acc, g0);
        accum8(acc, g1);
        accum8(acc, g2);
        accum8(acc, g3);
    }
    for (; b < nb; b++) {
        int i0 = clb[0];
        clb += 4;
        uint4 g0 = *(const uint4*)(G + (size_t)i0 * DIM + q * 8);
        accum8(acc, g0);
    }

#pragma unroll
    for (int j = 0; j < 8; j++) {
        acc[j] += __shfl_xor(acc[j], 16);
        acc[j] += __shfl_xor(acc[j], 32);
    }

    if (quarter == 0) {
        uint4 sv = *(const uint4*)(G + (size_t)node * DIM + q * 8);
        float4 b0 = *(const float4*)(bias + q * 8);
        float4 b1 = *(const float4*)(bias + q * 8 + 4);
        float* op = out + (size_t)node * DIM + q * 8;
        float4 r0, r1;
        r0.x = acc[0] + e1 * bf16lo(sv.x) + b0.x;
        r0.y = acc[1] + e1 * bf16hi(sv.x) + b0.y;
        r0.z = acc[2] + e1 * bf16lo(sv.y) + b0.z;
        r0.w = acc[3] + e1 * bf16hi(sv.y) + b0.w;
        r1.x = acc[4] + e1 * bf16lo(sv.z) + b1.x;
        r1.y = acc[5] + e1 * bf16hi(sv.z) + b1.y;
        r1.z = acc[6] + e1 * bf16lo(sv.w) + b1.z;
        r1.w = acc[7] + e1 * bf16hi(sv.w) + b1.w;
        *(float4*)op = r0;
        *(float4*)(op + 4) = r1;
    }
}

// ---------------- launch ----------------

extern "C" void kernel_launch(void* const* d_in, const int* in_sizes, int n_in,
                              void* d_out, int out_size, void* d_ws, size_t ws_size,
                              hipStream_t stream) {
    const float* feats = (const float*)d_in[0];
    const int* esrc = (const int*)d_in[1];
    const int* edst = (const int*)d_in[2];
    const float* Wm[3] = {(const float*)d_in[3], (const float*)d_in[6], (const float*)d_in[9]};
    const float* Bv[3] = {(const float*)d_in[4], (const float*)d_in[7], (const float*)d_in[10]};
    const float* Ev[3] = {(const float*)d_in[5], (const float*)d_in[8], (const float*)d_in[11]};
    float* out = (float*)d_out;

    char* ws = (char*)d_ws;
    unsigned short* bufG = (unsigned short*)(ws);        // 25,600,256 B : [100001][128] bf16 (G_A)
    int* ebuf       = (int*)(ws + 25600512);             // 12,800,000 B packed (src<<8|dst&255)
    int* csr        = (int*)(ws + 38400512);             // 16,003,072 B padded csr
    int* offsets    = (int*)(ws + 54411776);             //    400,000 B
    int* nbArr      = (int*)(ws + 54811776);             //    400,000 B
    int* bucketTotal= (int*)(ws + 55211776);             //      1,568 B
    int* bucketBase = (int*)(ws + 55213376);             //      1,572 B
    int* bucketCur  = (int*)(ws + 55215040);             //      1,568 B
    int* bhArr      = (int*)(ws + 55216640);             //  1,226,176 B per-block bucket hists
    unsigned short* wfrag = (unsigned short*)(ws + 56442816);  // 6 x 32,768 B: Wh0,Wl0,Wh1,Wl1,Wh2,Wl2

    unsigned short* G_A = bufG;
    unsigned short* G_B = (unsigned short*)d_out;  // 25.6MB bf16 scratch inside the 51.2MB
                                                   // output buffer; dead before agg3 overwrites out

    // W fragment prep (split-bf16, fragment-linear), all 3 layers in one launch
    prepw_k<<<96, 64, 0, stream>>>(Wm[0], Wm[1], Wm[2], wfrag);

    // CSR build: bucket counting sort (stores de-scattered via LDS reordering)
    hipMemsetAsync(bucketTotal, 0, NBP * sizeof(int), stream);
    bhist_k<<<EB_BLOCKS, 256, 0, stream>>>(edst, bucketTotal, bhArr);
    bscan_k<<<1, 512, 0, stream>>>(bucketTotal, bucketBase, bucketCur);
    bscatter_k<<<EB_BLOCKS, 512, 0, stream>>>(esrc, edst, bhArr, bucketCur, ebuf);
    bfinal_k<<<NBUCK, 256, 0, stream>>>(ebuf, bucketBase, offsets, nbArr, csr);

    // layer 1 gemm: G_A = bf16(feats @ W0)
    gemm_k<<<(N_NODES + 64) / 64, 256, 0, stream>>>(feats, wfrag, wfrag + 16384, G_A);
    // fused agg1+gemm2: G_B = bf16(h1' @ W1)
    aggemm_k<<<N_NODES / 16, 512, 0, stream>>>(G_A, offsets, nbArr, csr, Bv[0], Ev[0],
                                               wfrag + 32768, wfrag + 49152, G_B);
    // fused agg2+gemm3: G_A = bf16(h2' @ W2)
    aggemm_k<<<N_NODES / 16, 512, 0, stream>>>(G_B, offsets, nbArr, csr, Bv[1], Ev[1],
                                               wfrag + 65536, wfrag + 81920, G_A);
    // final agg: out = (1+eps)g3 + agg(g3) + b3  (f32)
    agg_k<<<N_NODES / 4, 256, 0, stream>>>(G_A, offsets, nbArr, csr, Bv[2], Ev[2], out);
}